// Round 4
// baseline (618.786 us; speedup 1.0000x reference)
//
#include <hip/hip_runtime.h>
#include <hip/hip_bf16.h>
#include <stdint.h>

#define N_NODES 50000
#define N_EDGES 800000
#define HID 128
#define NODE_IN 16
#define NODE_OUT 3
#define NODE_TILES 782     // ceil(50000 / 64)
#define SCAN_BLOCKS 196    // ceil(50000 / 256)
#define EDGE_BLOCKS 3125   // 800000 / 256, one edge per thread in k1
#define MFOLD_BLOCKS 192   // 3*16384 / 256
#define DG 32              // dests per edge-kernel block
#define DBLOCKS 1563       // ceil(50000 / 32)

typedef __attribute__((ext_vector_type(8))) short short8;
typedef __attribute__((ext_vector_type(4))) float f32x4;
typedef __attribute__((ext_vector_type(4))) unsigned int u32x4;

__device__ __forceinline__ unsigned short f2bf(float f) {
    union { float f; unsigned int u; } v; v.f = f;
    unsigned int u = v.u;
    u += 0x7fff + ((u >> 16) & 1);   // round-to-nearest-even
    return (unsigned short)(u >> 16);
}
__device__ __forceinline__ float bf2f(unsigned short s) {
    union { unsigned int u; float f; } v; v.u = ((unsigned int)s) << 16;
    return v.f;
}
__device__ __forceinline__ float bfu_lo(unsigned int u) {
    union { unsigned int u; float f; } v; v.u = u << 16; return v.f;
}
__device__ __forceinline__ float bfu_hi(unsigned int u) {
    union { unsigned int u; float f; } v; v.u = u & 0xffff0000u; return v.f;
}
// 2x f32 -> packed bf16 (RNE), single HW instruction on gfx950
__device__ __forceinline__ unsigned int cvt_pk_bf16(float lo, float hi) {
    unsigned int r;
    asm("v_cvt_pk_bf16_f32 %0, %1, %2" : "=v"(r) : "v"(lo), "v"(hi));
    return r;
}

// ---------------- K1: degree histogram (+ per-edge rank) + M-fold ----------------
__global__ __launch_bounds__(256) void k1_hist_mfold(
    const int* __restrict__ colp, int* __restrict__ cnt, int* __restrict__ rank,
    const float* __restrict__ edge_w2, const float* __restrict__ node_w1,
    const float* __restrict__ edge_b2,
    float* __restrict__ Mtmp, float* __restrict__ Vtmp) {
    int b = blockIdx.x, t = threadIdx.x;
    if (b < EDGE_BLOCKS) {
        int e = b * 256 + t;   // exact: 3125*256 = 800000
        rank[e] = atomicAdd(&cnt[colp[e]], 1);   // old value = within-dest rank
    } else {
        int d = (b - EDGE_BLOCKS) * 256 + t;     // exact: 192*256 = 49152 = 3*16384
        int L = d / 16384, rem = d & 16383;
        int k = rem >> 7, n = rem & 127;
        const float* w2  = edge_w2 + (size_t)L * 16384;
        const float* w1b = node_w1 + (size_t)L * 32768 + 16384;   // bottom-half rows
        float acc = 0.f;
        #pragma unroll 4
        for (int j = 0; j < 128; j++) acc += w2[k * 128 + j] * w1b[j * 128 + n];
        Mtmp[d] = acc;
        if (k == 0) {
            const float* b2 = edge_b2 + (size_t)L * 128;
            float vv = 0.f;
            #pragma unroll 4
            for (int j = 0; j < 128; j++) vv += b2[j] * w1b[j * 128 + n];
            Vtmp[L * 128 + n] = vv;
        }
    }
}

// ---------------- K2a: parallel scan1 (blocks < SCAN_BLOCKS) + weight swizzles ----------------
// swz per-layer layout: +0 edge w1cat (32768), [32768..49152) unused,
//                       +49152 node w1-modified [W1top; M] (32768), +81920 node w2 (16384)
__global__ __launch_bounds__(256) void k2a_scan1_swizzle(
    const int* __restrict__ cnt, int* __restrict__ ex, int* __restrict__ bsums,
    const float* __restrict__ edge_w1, const float* __restrict__ node_w1,
    const float* __restrict__ node_w2, const float* __restrict__ Mtmp,
    unsigned short* __restrict__ swz) {
    __shared__ int s[256];
    int b = blockIdx.x, t = threadIdx.x;
    if (b < SCAN_BLOCKS) {
        int i = b * 256 + t;
        int v = (i < N_NODES) ? cnt[i] : 0;
        s[t] = v;
        __syncthreads();
        for (int off = 1; off < 256; off <<= 1) {
            int u = (t >= off) ? s[t - off] : 0;
            __syncthreads();
            s[t] += u;
            __syncthreads();
        }
        if (i < N_NODES) ex[i] = s[t] - v;
        if (t == 255) bsums[b] = s[255];
    } else {
        for (int d = (b - SCAN_BLOCKS) * 256 + t; d < 3 * 98304;
             d += (gridDim.x - SCAN_BLOCKS) * 256) {
            int L = d / 98304;
            int rem = d - L * 98304;
            unsigned short* base = swz + L * 98304;
            if (rem < 32768) {
                // edge w1 combined [128 x 256] B-frags (16 n-tiles)
                const float* w1 = edge_w1 + (size_t)L * 32768;
                int j = rem & 7, ll = (rem >> 3) & 63, tt = rem >> 9;
                int nt = tt & 15, kt = tt >> 4;
                int k = kt * 32 + ((ll >> 4) << 3) + j;
                int cc = nt * 16 + (ll & 15);
                float v = (cc < 128) ? w1[k * 128 + cc] : w1[(128 + k) * 128 + (cc - 128)];
                base[rem] = f2bf(v);
            } else if (rem < 49152) {
                // unused slot (edge w2 folded into node w1 via M)
            } else if (rem < 81920) {
                int d2 = rem - 49152;
                int j = d2 & 7, ll = (d2 >> 3) & 63, tt = d2 >> 9;
                int nt = tt & 7, kt = tt >> 3;
                int k = kt * 32 + ((ll >> 4) << 3) + j, n = (nt << 4) + (ll & 15);
                float v = (k < 128) ? node_w1[(size_t)L * 32768 + k * 128 + n]
                                    : Mtmp[(size_t)L * 16384 + (k - 128) * 128 + n];
                base[rem] = f2bf(v);
            } else {
                int d2 = rem - 81920;
                const float* src = node_w2 + (size_t)L * 16384;
                int j = d2 & 7, ll = (d2 >> 3) & 63, tt = d2 >> 9;
                int nt = tt & 7, kt = tt >> 3;
                int k = kt * 32 + ((ll >> 4) << 3) + j, n = (nt << 4) + (ll & 15);
                base[rem] = f2bf(src[k * 128 + n]);
            }
        }
    }
}

// ---------------- K3a: scatter with inline scan2 + global segment starts ex2 ----------------
__global__ __launch_bounds__(256) void k3a_scatter(
    const int* __restrict__ rowp, const int* __restrict__ colp,
    const int* __restrict__ ex, const int* __restrict__ bsums,
    const int* __restrict__ rank, int2* __restrict__ rc_sorted,
    int* __restrict__ ex2) {
    __shared__ int sc[256];
    __shared__ int ls[SCAN_BLOCKS];
    int t = threadIdx.x;
    // redundant per-block exclusive scan of the 196 block sums (replaces k2b)
    int v = (t < SCAN_BLOCKS) ? bsums[t] : 0;
    sc[t] = v;
    __syncthreads();
    for (int off = 1; off < 256; off <<= 1) {
        int u = (t >= off) ? sc[t - off] : 0;
        __syncthreads();
        sc[t] += u;
        __syncthreads();
    }
    if (t < SCAN_BLOCKS) ls[t] = sc[t] - v;
    __syncthreads();

    int b = blockIdx.x;
    // global exclusive segment starts (consumed by ownership-based edge_kernel)
    if (b < SCAN_BLOCKS) {
        int i = b * 256 + t;
        if (i < N_NODES) ex2[i] = ex[i] + ls[b];
    }

    int e = b * 256 + t;
    if (e >= N_EDGES) return;
    int c = colp[e];
    int pos = ex[c] + ls[c >> 8] + rank[e];
    rc_sorted[pos] = make_int2(rowp[e], c);
}

// ---------------- K3b: encoder + S/D layer 0 (D gets +edge_b1[0] folded) ----------------
__global__ __launch_bounds__(256, 4) void k3b_encoder_sd(
    const float* __restrict__ x, const float* __restrict__ enc_w, const float* __restrict__ enc_b,
    const unsigned short* __restrict__ w1c, const float* __restrict__ eb1,
    unsigned short* __restrict__ h,
    unsigned short* __restrict__ S, unsigned short* __restrict__ D)
{
    __shared__ float wts[NODE_IN * HID];
    __shared__ float bts[HID];
    __shared__ float xs[64][NODE_IN];
    __shared__ unsigned short hs[64][136];
    int t = threadIdx.x, wave = t >> 6, l = t & 63, q = l >> 4, l16 = l & 15;
    int n0 = blockIdx.x * 64;
    int nt0s = wave * 4;

    for (int i = t; i < NODE_IN * HID; i += 256) wts[i] = enc_w[i];
    if (t < HID) bts[t] = enc_b[t];
    for (int i = t; i < 64 * NODE_IN; i += 256) {
        int nl = i >> 4, ii = i & 15;
        int n = n0 + nl;
        xs[nl][ii] = (n < N_NODES) ? x[n * NODE_IN + ii] : 0.f;
    }
    short8 wr[4][4];
    #pragma unroll
    for (int kt = 0; kt < 4; kt++)
        #pragma unroll
        for (int i = 0; i < 4; i++)
            wr[kt][i] = *(const short8*)(w1c + ((kt * 16 + nt0s + i) * 64 + l) * 8);
    __syncthreads();

    for (int o = t; o < 64 * HID; o += 256) {
        int nl = o >> 7, cc = o & 127;
        float acc = bts[cc];
        #pragma unroll
        for (int i = 0; i < NODE_IN; i++) acc += xs[nl][i] * wts[i * HID + cc];
        unsigned short hb = f2bf(acc);
        hs[nl][cc] = hb;
        int n = n0 + nl;
        if (n < N_NODES) h[n * HID + cc] = hb;
    }
    __syncthreads();

    f32x4 acc[4][4];
    #pragma unroll
    for (int g = 0; g < 4; g++)
        #pragma unroll
        for (int i = 0; i < 4; i++) acc[g][i] = (f32x4){0.f, 0.f, 0.f, 0.f};
    #pragma unroll
    for (int kt = 0; kt < 4; kt++) {
        #pragma unroll
        for (int g = 0; g < 4; g++) {
            short8 a = *(const short8*)&hs[g * 16 + l16][kt * 32 + q * 8];
            #pragma unroll
            for (int i = 0; i < 4; i++)
                acc[g][i] = __builtin_amdgcn_mfma_f32_16x16x32_bf16(a, wr[kt][i], acc[g][i], 0, 0, 0);
        }
    }
    #pragma unroll
    for (int i = 0; i < 4; i++) {
        int cc = (nt0s + i) * 16 + l16;
        float badd = 0.f;
        if (cc >= 128) badd = eb1[cc - 128];   // fold edge_b1[L=0] into D
        #pragma unroll
        for (int g = 0; g < 4; g++)
            #pragma unroll
            for (int r = 0; r < 4; r++) {
                int n = n0 + g * 16 + q * 4 + r;
                if (n < N_NODES) {
                    unsigned short v = f2bf(acc[g][i][r] + badd);
                    if (cc < 128) S[n * HID + cc] = v;
                    else          D[n * HID + (cc - 128)] = v;
                }
            }
    }
}

// ---------------- edge: dest-ownership blocks, ZERO global atomics ----------------
// rc_sorted is dest-sorted. Block owns DG=32 consecutive dests (edges
// ex2[d0]..ex2[d0+DG]); stages 64-edge tiles (cvt_pk relu to LDS), segment-
// reduces into a LDS accumulator (ds_add_f32), then writes its dests to aggH
// with plain coalesced stores exactly once. aggH never needs zeroing.
// LDS = 17,408 + 512 + 16,384 = 34,304 B -> 4 blocks/CU.
__global__ __launch_bounds__(256, 4) void edge_kernel(
    const unsigned short* __restrict__ S, const unsigned short* __restrict__ D,
    const int2* __restrict__ rc_sorted, const int* __restrict__ ex2,
    float* __restrict__ aggH)
{
    __shared__ unsigned short hid_s[64][136];   // bf16 relu outputs
    __shared__ int row_s[64], col_s[64];
    __shared__ float aggL[DG][HID];             // per-dest accumulator
    int t = threadIdx.x;
    int l = t & 63, w = t >> 6;
    int ch = l & 15, eg = l >> 4;
    int rbase = w * 16;
    int c128 = t & 127, r0 = (t >> 7) * 32;

    // XCD-chunked bijective mapping: xcd owns a contiguous range of dest-blocks
    const int q = DBLOCKS / 8, r = DBLOCKS % 8;   // 195, 3
    int xcd = blockIdx.x & 7, slot = blockIdx.x >> 3;
    int cntx = q + (xcd < r);
    if (slot >= cntx) return;
    int myb = xcd * q + (xcd < r ? xcd : r) + slot;

    int d0 = myb * DG;
    int d1 = d0 + DG; if (d1 > N_NODES) d1 = N_NODES;
    int eStart = ex2[d0];
    int eEnd = (d1 < N_NODES) ? ex2[d1] : N_EDGES;

    // zero the accumulator
    #pragma unroll
    for (int o = t; o < DG * HID; o += 256) aggL[o >> 7][o & 127] = 0.f;

    int nst = (eEnd - eStart + 63) >> 6;
    for (int s = 0; s < nst; s++) {
        int es0 = eStart + s * 64;
        if (l < 16) {
            int e = es0 + rbase + l;
            int2 rc = (e < eEnd) ? rc_sorted[e] : make_int2(0, d0);
            row_s[rbase + l] = rc.x;
            col_s[rbase + l] = rc.y;
        }
        asm volatile("s_waitcnt lgkmcnt(0)" ::: "memory");
        __builtin_amdgcn_sched_barrier(0);

        #pragma unroll
        for (int it = 0; it < 4; it++) {
            int el = rbase + it * 4 + eg;
            u32x4 o = (u32x4){0u, 0u, 0u, 0u};
            if (es0 + el < eEnd) {
                int rr = row_s[el], c = col_s[el];
                short8 sv = *(const short8*)(S + (size_t)rr * HID + ch * 8);
                short8 dv = *(const short8*)(D + (size_t)c * HID + ch * 8);
                #pragma unroll
                for (int p = 0; p < 4; p++) {
                    unsigned int us = ((const unsigned int*)&sv)[p];
                    unsigned int ud = ((const unsigned int*)&dv)[p];
                    float v0 = bfu_lo(us) + bfu_lo(ud);   // b1 folded into D
                    float v1 = bfu_hi(us) + bfu_hi(ud);
                    v0 = v0 > 0.f ? v0 : 0.f;
                    v1 = v1 > 0.f ? v1 : 0.f;
                    o[p] = cvt_pk_bf16(v0, v1);
                }
            }
            *(u32x4*)&hid_s[el][ch * 8] = o;
        }
        __syncthreads();   // staging + col_s visible block-wide (and aggL init on s==0)

        // segment reduce: thread owns channel c128 over rows [r0, r0+32)
        float acc = 0.f;
        int cur = col_s[r0];
        #pragma unroll
        for (int i0 = 0; i0 < 32; i0 += 4) {
            int4 c4 = *(const int4*)&col_s[r0 + i0];
            #pragma unroll
            for (int j = 0; j < 4; j++) {
                int c = ((const int*)&c4)[j];
                if (c != cur) {
                    atomicAdd(&aggL[cur - d0][c128], acc);   // LDS ds_add_f32
                    acc = 0.f;
                    cur = c;
                }
                acc += bf2f(hid_s[r0 + i0 + j][c128]);
            }
        }
        atomicAdd(&aggL[cur - d0][c128], acc);
        __syncthreads();   // reduce done before next tile's staging overwrites
    }

    // writeout: exactly-once plain stores (no atomics, no zeroing needed elsewhere)
    #pragma unroll
    for (int o = t; o < DG * HID; o += 256) {
        int d = d0 + (o >> 7);
        if (d < d1) aggH[(size_t)d * HID + (o & 127)] = aggL[o >> 7][o & 127];
    }
}

// ---------------- node MLP (folded GEMM1) + residual + (next S/D | decoder) ----------------
template<int LAST>
__global__ __launch_bounds__(256, 4) void node_kernel(
    unsigned short* __restrict__ h, float* __restrict__ aggH, const int* __restrict__ cnt,
    const unsigned short* __restrict__ w1m_s, const float* __restrict__ b1,
    const float* __restrict__ vfold,
    const unsigned short* __restrict__ w2s, const float* __restrict__ b2,
    const unsigned short* __restrict__ w1c_next, const float* __restrict__ eb1n,
    unsigned short* __restrict__ S, unsigned short* __restrict__ D,
    const float* __restrict__ dec_w, const float* __restrict__ dec_b, float* __restrict__ out)
{
    __shared__ unsigned short in_h[64][136];   // old h -> new h after residual
    __shared__ unsigned short in_a[64][136];   // bf16(aggH); reused as hid after GEMM1
    __shared__ int cnt_s[64];
    __shared__ float dw[HID * NODE_OUT];
    __shared__ float db[NODE_OUT];
    int t = threadIdx.x, wave = t >> 6, l = t & 63, q = l >> 4, l16 = l & 15;
    int nt0 = wave * 2, nt0s = wave * 4;
    int n0 = blockIdx.x * 64;

    if (LAST) {
        for (int i = t; i < HID * NODE_OUT; i += 256) dw[i] = dec_w[i];
        if (t < NODE_OUT) db[t] = dec_b[t];
    }

    // stage: h -> in_h, bf16(aggH) -> in_a (no re-zero: edge_kernel overwrites), cnt
    #pragma unroll
    for (int it = 0; it < 8; it++) {
        int g = it * 256 + t;
        int nl = g >> 5, sub = g & 31, half = sub >> 4, li = sub & 15;
        int n = n0 + nl;
        short8 v = (short8){0, 0, 0, 0, 0, 0, 0, 0};
        if (n < N_NODES) {
            if (half == 0) {
                v = *(const short8*)(h + n * HID + li * 8);
            } else {
                const float* ap = aggH + n * HID + li * 8;
                f32x4 a0 = *(const f32x4*)ap, a1 = *(const f32x4*)(ap + 4);
                unsigned int* vp = (unsigned int*)&v;
                vp[0] = cvt_pk_bf16(a0[0], a0[1]);
                vp[1] = cvt_pk_bf16(a0[2], a0[3]);
                vp[2] = cvt_pk_bf16(a1[0], a1[1]);
                vp[3] = cvt_pk_bf16(a1[2], a1[3]);
            }
        }
        if (half == 0) *(short8*)&in_h[nl][li * 8] = v;
        else           *(short8*)&in_a[nl][li * 8] = v;
    }
    if (t < 64) cnt_s[t] = (n0 + t < N_NODES) ? cnt[n0 + t] : 0;
    __syncthreads();

    float b1r0 = b1[nt0 * 16 + l16], b1r1 = b1[(nt0 + 1) * 16 + l16];
    float vr0 = vfold[nt0 * 16 + l16], vr1 = vfold[(nt0 + 1) * 16 + l16];
    float b2r0 = b2[nt0 * 16 + l16], b2r1 = b2[(nt0 + 1) * 16 + l16];

    // GEMM1 (K=256, B = [W1top; M] folded): h@W1top + aggH@M
    f32x4 acc[4][2];
    #pragma unroll
    for (int g = 0; g < 4; g++)
        #pragma unroll
        for (int j = 0; j < 2; j++) acc[g][j] = (f32x4){0.f, 0.f, 0.f, 0.f};
    #pragma unroll
    for (int kt = 0; kt < 8; kt++) {
        short8 b0 = *(const short8*)(w1m_s + ((kt * 8 + nt0)     * 64 + l) * 8);
        short8 b1v = *(const short8*)(w1m_s + ((kt * 8 + nt0 + 1) * 64 + l) * 8);
        #pragma unroll
        for (int g = 0; g < 4; g++) {
            short8 a = (kt < 4) ? *(const short8*)&in_h[g * 16 + l16][kt * 32 + q * 8]
                                : *(const short8*)&in_a[g * 16 + l16][(kt - 4) * 32 + q * 8];
            acc[g][0] = __builtin_amdgcn_mfma_f32_16x16x32_bf16(a, b0, acc[g][0], 0, 0, 0);
            acc[g][1] = __builtin_amdgcn_mfma_f32_16x16x32_bf16(a, b1v, acc[g][1], 0, 0, 0);
        }
    }
    __syncthreads();   // all in_a reads complete before hid overwrite

    // epilogue: + b1 + deg*v -> relu -> hid (aliases in_a)
    #pragma unroll
    for (int j = 0; j < 2; j++) {
        float bv = j ? b1r1 : b1r0;
        float vv = j ? vr1 : vr0;
        #pragma unroll
        for (int g = 0; g < 4; g++)
            #pragma unroll
            for (int r = 0; r < 4; r++) {
                int m2 = g * 16 + q * 4 + r;
                float v = acc[g][j][r] + bv + (float)cnt_s[m2] * vv;
                v = v > 0.f ? v : 0.f;
                in_a[m2][(nt0 + j) * 16 + l16] = f2bf(v);
            }
    }
    __syncthreads();

    // GEMM2n (K=128) -> residual -> h + in_h
    f32x4 acc2[4][2];
    #pragma unroll
    for (int g = 0; g < 4; g++)
        #pragma unroll
        for (int j = 0; j < 2; j++) acc2[g][j] = (f32x4){0.f, 0.f, 0.f, 0.f};
    #pragma unroll
    for (int kt = 0; kt < 4; kt++) {
        short8 b0 = *(const short8*)(w2s + ((kt * 8 + nt0)     * 64 + l) * 8);
        short8 b1v = *(const short8*)(w2s + ((kt * 8 + nt0 + 1) * 64 + l) * 8);
        #pragma unroll
        for (int g = 0; g < 4; g++) {
            short8 a = *(const short8*)&in_a[g * 16 + l16][kt * 32 + q * 8];
            acc2[g][0] = __builtin_amdgcn_mfma_f32_16x16x32_bf16(a, b0, acc2[g][0], 0, 0, 0);
            acc2[g][1] = __builtin_amdgcn_mfma_f32_16x16x32_bf16(a, b1v, acc2[g][1], 0, 0, 0);
        }
    }
    #pragma unroll
    for (int j = 0; j < 2; j++) {
        float bv = j ? b2r1 : b2r0;
        #pragma unroll
        for (int g = 0; g < 4; g++)
            #pragma unroll
            for (int r = 0; r < 4; r++) {
                float v = acc2[g][j][r] + bv;
                int m2 = g * 16 + q * 4 + r;
                int n = n0 + m2;
                if (n < N_NODES) {
                    int c = (nt0 + j) * 16 + l16;
                    unsigned short nh = f2bf(bf2f(in_h[m2][c]) + v);   // residual (same-thread cell)
                    if (!LAST) h[n * HID + c] = nh;
                    in_h[m2][c] = nh;
                }
            }
    }
    __syncthreads();

    if (!LAST) {
        // next-layer S/D from new h (in_h), in 2 register-light passes
        // D gets +edge_b1[L+1] folded so edge_kernel skips the bias add
        #pragma unroll
        for (int p = 0; p < 2; p++) {
            short8 wr[4][2];
            #pragma unroll
            for (int kt = 0; kt < 4; kt++) {
                wr[kt][0] = *(const short8*)(w1c_next + ((kt * 16 + nt0s + p * 2)     * 64 + l) * 8);
                wr[kt][1] = *(const short8*)(w1c_next + ((kt * 16 + nt0s + p * 2 + 1) * 64 + l) * 8);
            }
            f32x4 accs[4][2];
            #pragma unroll
            for (int g = 0; g < 4; g++)
                #pragma unroll
                for (int i = 0; i < 2; i++) accs[g][i] = (f32x4){0.f, 0.f, 0.f, 0.f};
            #pragma unroll
            for (int kt = 0; kt < 4; kt++) {
                #pragma unroll
                for (int g = 0; g < 4; g++) {
                    short8 a = *(const short8*)&in_h[g * 16 + l16][kt * 32 + q * 8];
                    accs[g][0] = __builtin_amdgcn_mfma_f32_16x16x32_bf16(a, wr[kt][0], accs[g][0], 0, 0, 0);
                    accs[g][1] = __builtin_amdgcn_mfma_f32_16x16x32_bf16(a, wr[kt][1], accs[g][1], 0, 0, 0);
                }
            }
            #pragma unroll
            for (int i = 0; i < 2; i++) {
                int c = (nt0s + p * 2 + i) * 16 + l16;
                float badd = 0.f;
                if (c >= 128) badd = eb1n[c - 128];
                #pragma unroll
                for (int g = 0; g < 4; g++)
                    #pragma unroll
                    for (int r = 0; r < 4; r++) {
                        int n = n0 + g * 16 + q * 4 + r;
                        if (n < N_NODES) {
                            unsigned short v = f2bf(accs[g][i][r] + badd);
                            if (c < 128) S[n * HID + c] = v;
                            else         D[n * HID + (c - 128)] = v;
                        }
                    }
            }
        }
    } else {
        // decoder: out = new_h @ dec_w + dec_b
        if (t < 64 * NODE_OUT) {
            int nl = t / 3, o = t - 3 * nl;
            int n = n0 + nl;
            if (n < N_NODES) {
                float a = db[o];
                #pragma unroll 4
                for (int k = 0; k < HID; k++) a += bf2f(in_h[nl][k]) * dw[k * 3 + o];
                out[n * 3 + o] = a;
            }
        }
    }
}

extern "C" void kernel_launch(void* const* d_in, const int* in_sizes, int n_in,
                              void* d_out, int out_size, void* d_ws, size_t ws_size,
                              hipStream_t stream) {
    const float* x       = (const float*)d_in[0];
    const int*   ei      = (const int*)d_in[1];
    const float* enc_w   = (const float*)d_in[2];
    const float* enc_b   = (const float*)d_in[3];
    const float* dec_w   = (const float*)d_in[4];
    const float* dec_b   = (const float*)d_in[5];
    const float* edge_w1 = (const float*)d_in[6];
    const float* edge_b1 = (const float*)d_in[7];
    const float* edge_w2 = (const float*)d_in[8];
    const float* edge_b2 = (const float*)d_in[9];
    const float* node_w1 = (const float*)d_in[10];
    const float* node_b1 = (const float*)d_in[11];
    const float* node_w2 = (const float*)d_in[12];
    const float* node_b2 = (const float*)d_in[13];

    char* ws = (char*)d_ws;
    unsigned short* h    = (unsigned short*)ws;                    // 12.8 MB
    float*          aggH = (float*)(ws + 12800000);                // 25.6 MB
    unsigned short* swz  = (unsigned short*)(ws + 38400000);       // 589,824 B
    int* cnt             = (int*)(ws + 38989824);                  // 200,000 B (degrees)
    int* ex              = (int*)(ws + 39189824);                  // 200,000 B
    int* bsums           = (int*)(ws + 39389824);                  // 1,024 B
    int2* rc_sorted      = (int2*)(ws + 39390848);                 // 6.4 MB
    unsigned short* Sbuf = (unsigned short*)(ws + 45790848);       // 12.8 MB
    unsigned short* Dbuf = (unsigned short*)(ws + 58590848);       // 12.8 MB
    float* Mtmp          = (float*)(ws + 71390848);                // 196,608 B
    float* Vtmp          = (float*)(ws + 71587456);                // 1,536 B
    int* ex2             = (int*)(ws + 71588992);                  // 200,000 B -> end 71,788,992
    // rank overlays the Dbuf region: written in k1, consumed in k3a,
    // before Dbuf's first write in k3b. No extra workspace.
    int* rank            = (int*)(ws + 58590848);                  // 3.2 MB (aliases Dbuf)

    const int* rowp = ei;            // edge_index[0] = source
    const int* colp = ei + N_EDGES;  // edge_index[1] = destination

    hipMemsetAsync(cnt, 0, (size_t)N_NODES * 4, stream);

    k1_hist_mfold<<<EDGE_BLOCKS + MFOLD_BLOCKS, 256, 0, stream>>>(
        colp, cnt, rank, edge_w2, node_w1, edge_b2, Mtmp, Vtmp);
    k2a_scan1_swizzle<<<SCAN_BLOCKS + 288, 256, 0, stream>>>(cnt, ex, bsums, edge_w1,
                                                             node_w1, node_w2, Mtmp, swz);
    k3a_scatter<<<3125, 256, 0, stream>>>(rowp, colp, ex, bsums, rank, rc_sorted, ex2);
    k3b_encoder_sd<<<NODE_TILES, 256, 0, stream>>>(x, enc_w, enc_b, swz /*L0 w1cat*/,
                                                   edge_b1 /*fold L0 bias into D*/, h,
                                                   Sbuf, Dbuf);

    for (int L = 0; L < 3; L++) {
        unsigned short* base = swz + (size_t)L * 98304;
        unsigned short* next = swz + (size_t)(L + 1) * 98304;   // w1cat of next layer
        edge_kernel<<<1568, 256, 0, stream>>>(Sbuf, Dbuf, rc_sorted, ex2, aggH);
        if (L < 2) {
            node_kernel<0><<<NODE_TILES, 256, 0, stream>>>(
                h, aggH, cnt,
                base + 49152, node_b1 + (size_t)L * HID, Vtmp + (size_t)L * HID,
                base + 81920, node_b2 + (size_t)L * HID,
                next, edge_b1 + (size_t)(L + 1) * HID, Sbuf, Dbuf, dec_w, dec_b, (float*)d_out);
        } else {
            node_kernel<1><<<NODE_TILES, 256, 0, stream>>>(
                h, aggH, cnt,
                base + 49152, node_b1 + (size_t)L * HID, Vtmp + (size_t)L * HID,
                base + 81920, node_b2 + (size_t)L * HID,
                base /*unused*/, edge_b1 /*unused*/, Sbuf, Dbuf, dec_w, dec_b, (float*)d_out);
        }
    }
}

// Round 5
// 385.243 us; speedup vs baseline: 1.6062x; 1.6062x over previous
//
#include <hip/hip_runtime.h>
#include <hip/hip_bf16.h>
#include <stdint.h>

#define N_NODES 50000
#define N_EDGES 800000
#define HID 128
#define NODE_IN 16
#define NODE_OUT 3
#define NODE_TILES 782     // ceil(50000 / 64)
#define SCAN_BLOCKS 196    // ceil(50000 / 256)
#define EDGE_BLOCKS 3125   // 800000 / 256, one edge per thread in k1
#define MFOLD_BLOCKS 192   // 3*16384 / 256
#define DG 32              // dests per edge-kernel block (16 groups x 2)
#define DBLOCKS 1563       // ceil(50000 / 32)

typedef __attribute__((ext_vector_type(8))) short short8;
typedef __attribute__((ext_vector_type(4))) float f32x4;
typedef __attribute__((ext_vector_type(4))) unsigned int u32x4;

__device__ __forceinline__ unsigned short f2bf(float f) {
    union { float f; unsigned int u; } v; v.f = f;
    unsigned int u = v.u;
    u += 0x7fff + ((u >> 16) & 1);   // round-to-nearest-even
    return (unsigned short)(u >> 16);
}
__device__ __forceinline__ float bf2f(unsigned short s) {
    union { unsigned int u; float f; } v; v.u = ((unsigned int)s) << 16;
    return v.f;
}
__device__ __forceinline__ float bfu_lo(unsigned int u) {
    union { unsigned int u; float f; } v; v.u = u << 16; return v.f;
}
__device__ __forceinline__ float bfu_hi(unsigned int u) {
    union { unsigned int u; float f; } v; v.u = u & 0xffff0000u; return v.f;
}
// 2x f32 -> packed bf16 (RNE), single HW instruction on gfx950
__device__ __forceinline__ unsigned int cvt_pk_bf16(float lo, float hi) {
    unsigned int r;
    asm("v_cvt_pk_bf16_f32 %0, %1, %2" : "=v"(r) : "v"(lo), "v"(hi));
    return r;
}

// ---------------- K1: degree histogram (+ per-edge rank) + M-fold ----------------
__global__ __launch_bounds__(256) void k1_hist_mfold(
    const int* __restrict__ colp, int* __restrict__ cnt, int* __restrict__ rank,
    const float* __restrict__ edge_w2, const float* __restrict__ node_w1,
    const float* __restrict__ edge_b2,
    float* __restrict__ Mtmp, float* __restrict__ Vtmp) {
    int b = blockIdx.x, t = threadIdx.x;
    if (b < EDGE_BLOCKS) {
        int e = b * 256 + t;   // exact: 3125*256 = 800000
        rank[e] = atomicAdd(&cnt[colp[e]], 1);   // old value = within-dest rank
    } else {
        int d = (b - EDGE_BLOCKS) * 256 + t;     // exact: 192*256 = 49152 = 3*16384
        int L = d / 16384, rem = d & 16383;
        int k = rem >> 7, n = rem & 127;
        const float* w2  = edge_w2 + (size_t)L * 16384;
        const float* w1b = node_w1 + (size_t)L * 32768 + 16384;   // bottom-half rows
        float acc = 0.f;
        #pragma unroll 4
        for (int j = 0; j < 128; j++) acc += w2[k * 128 + j] * w1b[j * 128 + n];
        Mtmp[d] = acc;
        if (k == 0) {
            const float* b2 = edge_b2 + (size_t)L * 128;
            float vv = 0.f;
            #pragma unroll 4
            for (int j = 0; j < 128; j++) vv += b2[j] * w1b[j * 128 + n];
            Vtmp[L * 128 + n] = vv;
        }
    }
}

// ---------------- K2a: parallel scan1 (blocks < SCAN_BLOCKS) + weight swizzles ----------------
// swz per-layer layout: +0 edge w1cat (32768), [32768..49152) unused,
//                       +49152 node w1-modified [W1top; M] (32768), +81920 node w2 (16384)
__global__ __launch_bounds__(256) void k2a_scan1_swizzle(
    const int* __restrict__ cnt, int* __restrict__ ex, int* __restrict__ bsums,
    const float* __restrict__ edge_w1, const float* __restrict__ node_w1,
    const float* __restrict__ node_w2, const float* __restrict__ Mtmp,
    unsigned short* __restrict__ swz) {
    __shared__ int s[256];
    int b = blockIdx.x, t = threadIdx.x;
    if (b < SCAN_BLOCKS) {
        int i = b * 256 + t;
        int v = (i < N_NODES) ? cnt[i] : 0;
        s[t] = v;
        __syncthreads();
        for (int off = 1; off < 256; off <<= 1) {
            int u = (t >= off) ? s[t - off] : 0;
            __syncthreads();
            s[t] += u;
            __syncthreads();
        }
        if (i < N_NODES) ex[i] = s[t] - v;
        if (t == 255) bsums[b] = s[255];
    } else {
        for (int d = (b - SCAN_BLOCKS) * 256 + t; d < 3 * 98304;
             d += (gridDim.x - SCAN_BLOCKS) * 256) {
            int L = d / 98304;
            int rem = d - L * 98304;
            unsigned short* base = swz + L * 98304;
            if (rem < 32768) {
                // edge w1 combined [128 x 256] B-frags (16 n-tiles)
                const float* w1 = edge_w1 + (size_t)L * 32768;
                int j = rem & 7, ll = (rem >> 3) & 63, tt = rem >> 9;
                int nt = tt & 15, kt = tt >> 4;
                int k = kt * 32 + ((ll >> 4) << 3) + j;
                int cc = nt * 16 + (ll & 15);
                float v = (cc < 128) ? w1[k * 128 + cc] : w1[(128 + k) * 128 + (cc - 128)];
                base[rem] = f2bf(v);
            } else if (rem < 49152) {
                // unused slot (edge w2 folded into node w1 via M)
            } else if (rem < 81920) {
                int d2 = rem - 49152;
                int j = d2 & 7, ll = (d2 >> 3) & 63, tt = d2 >> 9;
                int nt = tt & 7, kt = tt >> 3;
                int k = kt * 32 + ((ll >> 4) << 3) + j, n = (nt << 4) + (ll & 15);
                float v = (k < 128) ? node_w1[(size_t)L * 32768 + k * 128 + n]
                                    : Mtmp[(size_t)L * 16384 + (k - 128) * 128 + n];
                base[rem] = f2bf(v);
            } else {
                int d2 = rem - 81920;
                const float* src = node_w2 + (size_t)L * 16384;
                int j = d2 & 7, ll = (d2 >> 3) & 63, tt = d2 >> 9;
                int nt = tt & 7, kt = tt >> 3;
                int k = kt * 32 + ((ll >> 4) << 3) + j, n = (nt << 4) + (ll & 15);
                base[rem] = f2bf(src[k * 128 + n]);
            }
        }
    }
}

// ---------------- K3a: row-only scatter with inline scan2 + global segment starts ex2 ----------------
__global__ __launch_bounds__(256) void k3a_scatter(
    const int* __restrict__ rowp, const int* __restrict__ colp,
    const int* __restrict__ ex, const int* __restrict__ bsums,
    const int* __restrict__ rank, int* __restrict__ rsrt,
    int* __restrict__ ex2) {
    __shared__ int sc[256];
    __shared__ int ls[SCAN_BLOCKS];
    int t = threadIdx.x;
    // redundant per-block exclusive scan of the 196 block sums (replaces k2b)
    int v = (t < SCAN_BLOCKS) ? bsums[t] : 0;
    sc[t] = v;
    __syncthreads();
    for (int off = 1; off < 256; off <<= 1) {
        int u = (t >= off) ? sc[t - off] : 0;
        __syncthreads();
        sc[t] += u;
        __syncthreads();
    }
    if (t < SCAN_BLOCKS) ls[t] = sc[t] - v;
    __syncthreads();

    int b = blockIdx.x;
    // global exclusive segment starts (consumed by ownership-based edge_kernel)
    if (b < SCAN_BLOCKS) {
        int i = b * 256 + t;
        if (i < N_NODES) ex2[i] = ex[i] + ls[b];
    }

    int e = b * 256 + t;
    if (e >= N_EDGES) return;
    int c = colp[e];
    int pos = ex[c] + ls[c >> 8] + rank[e];
    rsrt[pos] = rowp[e];   // dest implied by position; edge_kernel owns dest ranges
}

// ---------------- K3b: encoder + S/D layer 0 (D gets +edge_b1[0] folded) ----------------
__global__ __launch_bounds__(256, 4) void k3b_encoder_sd(
    const float* __restrict__ x, const float* __restrict__ enc_w, const float* __restrict__ enc_b,
    const unsigned short* __restrict__ w1c, const float* __restrict__ eb1,
    unsigned short* __restrict__ h,
    unsigned short* __restrict__ S, unsigned short* __restrict__ D)
{
    __shared__ float wts[NODE_IN * HID];
    __shared__ float bts[HID];
    __shared__ float xs[64][NODE_IN];
    __shared__ unsigned short hs[64][136];
    int t = threadIdx.x, wave = t >> 6, l = t & 63, q = l >> 4, l16 = l & 15;
    int n0 = blockIdx.x * 64;
    int nt0s = wave * 4;

    for (int i = t; i < NODE_IN * HID; i += 256) wts[i] = enc_w[i];
    if (t < HID) bts[t] = enc_b[t];
    for (int i = t; i < 64 * NODE_IN; i += 256) {
        int nl = i >> 4, ii = i & 15;
        int n = n0 + nl;
        xs[nl][ii] = (n < N_NODES) ? x[n * NODE_IN + ii] : 0.f;
    }
    short8 wr[4][4];
    #pragma unroll
    for (int kt = 0; kt < 4; kt++)
        #pragma unroll
        for (int i = 0; i < 4; i++)
            wr[kt][i] = *(const short8*)(w1c + ((kt * 16 + nt0s + i) * 64 + l) * 8);
    __syncthreads();

    for (int o = t; o < 64 * HID; o += 256) {
        int nl = o >> 7, cc = o & 127;
        float acc = bts[cc];
        #pragma unroll
        for (int i = 0; i < NODE_IN; i++) acc += xs[nl][i] * wts[i * HID + cc];
        unsigned short hb = f2bf(acc);
        hs[nl][cc] = hb;
        int n = n0 + nl;
        if (n < N_NODES) h[n * HID + cc] = hb;
    }
    __syncthreads();

    f32x4 acc[4][4];
    #pragma unroll
    for (int g = 0; g < 4; g++)
        #pragma unroll
        for (int i = 0; i < 4; i++) acc[g][i] = (f32x4){0.f, 0.f, 0.f, 0.f};
    #pragma unroll
    for (int kt = 0; kt < 4; kt++) {
        #pragma unroll
        for (int g = 0; g < 4; g++) {
            short8 a = *(const short8*)&hs[g * 16 + l16][kt * 32 + q * 8];
            #pragma unroll
            for (int i = 0; i < 4; i++)
                acc[g][i] = __builtin_amdgcn_mfma_f32_16x16x32_bf16(a, wr[kt][i], acc[g][i], 0, 0, 0);
        }
    }
    #pragma unroll
    for (int i = 0; i < 4; i++) {
        int cc = (nt0s + i) * 16 + l16;
        float badd = 0.f;
        if (cc >= 128) badd = eb1[cc - 128];   // fold edge_b1[L=0] into D
        #pragma unroll
        for (int g = 0; g < 4; g++)
            #pragma unroll
            for (int r = 0; r < 4; r++) {
                int n = n0 + g * 16 + q * 4 + r;
                if (n < N_NODES) {
                    unsigned short v = f2bf(acc[g][i][r] + badd);
                    if (cc < 128) S[n * HID + cc] = v;
                    else          D[n * HID + (cc - 128)] = v;
                }
            }
    }
}

// ---------------- edge: register-accumulating dest-ownership, no LDS / barriers / atomics ----------------
// 16-lane group (8 ch/lane = 128 ch) owns 2 consecutive dests. Walks its edges
// serially with depth-1 S prefetch, acc += relu(S[row]+D[dest]) in 8 f32 regs
// (D loaded once per dest, b1 pre-folded), flushes each dest with 2 plain
// f32x4 stores. aggH fully written (incl. degree-0 dests) -> no zeroing anywhere.
__global__ __launch_bounds__(256, 8) void edge_kernel(
    const unsigned short* __restrict__ S, const unsigned short* __restrict__ D,
    const int* __restrict__ rsrt, const int* __restrict__ ex2,
    float* __restrict__ aggH)
{
    int t = threadIdx.x;
    int g16 = t >> 4, ch = t & 15;

    // XCD-chunked bijective mapping: xcd owns a contiguous range of dest-blocks
    const int q = DBLOCKS / 8, r = DBLOCKS % 8;   // 195, 3
    int xcd = blockIdx.x & 7, slot = blockIdx.x >> 3;
    int cntx = q + (xcd < r);
    if (slot >= cntx) return;
    int myb = xcd * q + (xcd < r ? xcd : r) + slot;

    int dbase = myb * DG + g16 * 2;

    #pragma unroll
    for (int di = 0; di < 2; di++) {
        int d = dbase + di;
        if (d >= N_NODES) break;
        int e0 = ex2[d];
        int e1 = (d + 1 < N_NODES) ? ex2[d + 1] : N_EDGES;

        // D row slice once per dest (b1 folded in)
        short8 dv = *(const short8*)(D + (size_t)d * HID + ch * 8);
        float dr[8];
        #pragma unroll
        for (int p = 0; p < 4; p++) {
            unsigned int ud = ((const unsigned int*)&dv)[p];
            dr[2 * p]     = bfu_lo(ud);
            dr[2 * p + 1] = bfu_hi(ud);
        }

        float a[8];
        #pragma unroll
        for (int j = 0; j < 8; j++) a[j] = 0.f;

        int e = e0;
        short8 sv_n = (short8){0,0,0,0,0,0,0,0};
        if (e < e1) {
            int rn = rsrt[e];
            sv_n = *(const short8*)(S + (size_t)rn * HID + ch * 8);
        }
        while (e < e1) {
            short8 sv = sv_n;
            int en = e + 1;
            if (en < e1) {
                int rn = rsrt[en];
                sv_n = *(const short8*)(S + (size_t)rn * HID + ch * 8);
            }
            #pragma unroll
            for (int p = 0; p < 4; p++) {
                unsigned int us = ((const unsigned int*)&sv)[p];
                float v0 = bfu_lo(us) + dr[2 * p];
                float v1 = bfu_hi(us) + dr[2 * p + 1];
                v0 = v0 > 0.f ? v0 : 0.f;
                v1 = v1 > 0.f ? v1 : 0.f;
                a[2 * p]     += v0;
                a[2 * p + 1] += v1;
            }
            e = en;
        }

        f32x4* dst = (f32x4*)(aggH + (size_t)d * HID + ch * 8);
        dst[0] = (f32x4){a[0], a[1], a[2], a[3]};
        dst[1] = (f32x4){a[4], a[5], a[6], a[7]};
    }
}

// ---------------- node MLP (folded GEMM1) + residual + (next S/D | decoder) ----------------
template<int LAST>
__global__ __launch_bounds__(256, 4) void node_kernel(
    unsigned short* __restrict__ h, float* __restrict__ aggH, const int* __restrict__ cnt,
    const unsigned short* __restrict__ w1m_s, const float* __restrict__ b1,
    const float* __restrict__ vfold,
    const unsigned short* __restrict__ w2s, const float* __restrict__ b2,
    const unsigned short* __restrict__ w1c_next, const float* __restrict__ eb1n,
    unsigned short* __restrict__ S, unsigned short* __restrict__ D,
    const float* __restrict__ dec_w, const float* __restrict__ dec_b, float* __restrict__ out)
{
    __shared__ unsigned short in_h[64][136];   // old h -> new h after residual
    __shared__ unsigned short in_a[64][136];   // bf16(aggH); reused as hid after GEMM1
    __shared__ int cnt_s[64];
    __shared__ float dw[HID * NODE_OUT];
    __shared__ float db[NODE_OUT];
    int t = threadIdx.x, wave = t >> 6, l = t & 63, q = l >> 4, l16 = l & 15;
    int nt0 = wave * 2, nt0s = wave * 4;
    int n0 = blockIdx.x * 64;

    if (LAST) {
        for (int i = t; i < HID * NODE_OUT; i += 256) dw[i] = dec_w[i];
        if (t < NODE_OUT) db[t] = dec_b[t];
    }

    // stage: h -> in_h, bf16(aggH) -> in_a (no re-zero: edge_kernel overwrites), cnt
    #pragma unroll
    for (int it = 0; it < 8; it++) {
        int g = it * 256 + t;
        int nl = g >> 5, sub = g & 31, half = sub >> 4, li = sub & 15;
        int n = n0 + nl;
        short8 v = (short8){0, 0, 0, 0, 0, 0, 0, 0};
        if (n < N_NODES) {
            if (half == 0) {
                v = *(const short8*)(h + n * HID + li * 8);
            } else {
                const float* ap = aggH + n * HID + li * 8;
                f32x4 a0 = *(const f32x4*)ap, a1 = *(const f32x4*)(ap + 4);
                unsigned int* vp = (unsigned int*)&v;
                vp[0] = cvt_pk_bf16(a0[0], a0[1]);
                vp[1] = cvt_pk_bf16(a0[2], a0[3]);
                vp[2] = cvt_pk_bf16(a1[0], a1[1]);
                vp[3] = cvt_pk_bf16(a1[2], a1[3]);
            }
        }
        if (half == 0) *(short8*)&in_h[nl][li * 8] = v;
        else           *(short8*)&in_a[nl][li * 8] = v;
    }
    if (t < 64) cnt_s[t] = (n0 + t < N_NODES) ? cnt[n0 + t] : 0;
    __syncthreads();

    float b1r0 = b1[nt0 * 16 + l16], b1r1 = b1[(nt0 + 1) * 16 + l16];
    float vr0 = vfold[nt0 * 16 + l16], vr1 = vfold[(nt0 + 1) * 16 + l16];
    float b2r0 = b2[nt0 * 16 + l16], b2r1 = b2[(nt0 + 1) * 16 + l16];

    // GEMM1 (K=256, B = [W1top; M] folded): h@W1top + aggH@M
    f32x4 acc[4][2];
    #pragma unroll
    for (int g = 0; g < 4; g++)
        #pragma unroll
        for (int j = 0; j < 2; j++) acc[g][j] = (f32x4){0.f, 0.f, 0.f, 0.f};
    #pragma unroll
    for (int kt = 0; kt < 8; kt++) {
        short8 b0 = *(const short8*)(w1m_s + ((kt * 8 + nt0)     * 64 + l) * 8);
        short8 b1v = *(const short8*)(w1m_s + ((kt * 8 + nt0 + 1) * 64 + l) * 8);
        #pragma unroll
        for (int g = 0; g < 4; g++) {
            short8 a = (kt < 4) ? *(const short8*)&in_h[g * 16 + l16][kt * 32 + q * 8]
                                : *(const short8*)&in_a[g * 16 + l16][(kt - 4) * 32 + q * 8];
            acc[g][0] = __builtin_amdgcn_mfma_f32_16x16x32_bf16(a, b0, acc[g][0], 0, 0, 0);
            acc[g][1] = __builtin_amdgcn_mfma_f32_16x16x32_bf16(a, b1v, acc[g][1], 0, 0, 0);
        }
    }
    __syncthreads();   // all in_a reads complete before hid overwrite

    // epilogue: + b1 + deg*v -> relu -> hid (aliases in_a)
    #pragma unroll
    for (int j = 0; j < 2; j++) {
        float bv = j ? b1r1 : b1r0;
        float vv = j ? vr1 : vr0;
        #pragma unroll
        for (int g = 0; g < 4; g++)
            #pragma unroll
            for (int r = 0; r < 4; r++) {
                int m2 = g * 16 + q * 4 + r;
                float v = acc[g][j][r] + bv + (float)cnt_s[m2] * vv;
                v = v > 0.f ? v : 0.f;
                in_a[m2][(nt0 + j) * 16 + l16] = f2bf(v);
            }
    }
    __syncthreads();

    // GEMM2n (K=128) -> residual -> h + in_h
    f32x4 acc2[4][2];
    #pragma unroll
    for (int g = 0; g < 4; g++)
        #pragma unroll
        for (int j = 0; j < 2; j++) acc2[g][j] = (f32x4){0.f, 0.f, 0.f, 0.f};
    #pragma unroll
    for (int kt = 0; kt < 4; kt++) {
        short8 b0 = *(const short8*)(w2s + ((kt * 8 + nt0)     * 64 + l) * 8);
        short8 b1v = *(const short8*)(w2s + ((kt * 8 + nt0 + 1) * 64 + l) * 8);
        #pragma unroll
        for (int g = 0; g < 4; g++) {
            short8 a = *(const short8*)&in_a[g * 16 + l16][kt * 32 + q * 8];
            acc2[g][0] = __builtin_amdgcn_mfma_f32_16x16x32_bf16(a, b0, acc2[g][0], 0, 0, 0);
            acc2[g][1] = __builtin_amdgcn_mfma_f32_16x16x32_bf16(a, b1v, acc2[g][1], 0, 0, 0);
        }
    }
    #pragma unroll
    for (int j = 0; j < 2; j++) {
        float bv = j ? b2r1 : b2r0;
        #pragma unroll
        for (int g = 0; g < 4; g++)
            #pragma unroll
            for (int r = 0; r < 4; r++) {
                float v = acc2[g][j][r] + bv;
                int m2 = g * 16 + q * 4 + r;
                int n = n0 + m2;
                if (n < N_NODES) {
                    int c = (nt0 + j) * 16 + l16;
                    unsigned short nh = f2bf(bf2f(in_h[m2][c]) + v);   // residual (same-thread cell)
                    if (!LAST) h[n * HID + c] = nh;
                    in_h[m2][c] = nh;
                }
            }
    }
    __syncthreads();

    if (!LAST) {
        // next-layer S/D from new h (in_h), in 2 register-light passes
        // D gets +edge_b1[L+1] folded so edge_kernel skips the bias add
        #pragma unroll
        for (int p = 0; p < 2; p++) {
            short8 wr[4][2];
            #pragma unroll
            for (int kt = 0; kt < 4; kt++) {
                wr[kt][0] = *(const short8*)(w1c_next + ((kt * 16 + nt0s + p * 2)     * 64 + l) * 8);
                wr[kt][1] = *(const short8*)(w1c_next + ((kt * 16 + nt0s + p * 2 + 1) * 64 + l) * 8);
            }
            f32x4 accs[4][2];
            #pragma unroll
            for (int g = 0; g < 4; g++)
                #pragma unroll
                for (int i = 0; i < 2; i++) accs[g][i] = (f32x4){0.f, 0.f, 0.f, 0.f};
            #pragma unroll
            for (int kt = 0; kt < 4; kt++) {
                #pragma unroll
                for (int g = 0; g < 4; g++) {
                    short8 a = *(const short8*)&in_h[g * 16 + l16][kt * 32 + q * 8];
                    accs[g][0] = __builtin_amdgcn_mfma_f32_16x16x32_bf16(a, wr[kt][0], accs[g][0], 0, 0, 0);
                    accs[g][1] = __builtin_amdgcn_mfma_f32_16x16x32_bf16(a, wr[kt][1], accs[g][1], 0, 0, 0);
                }
            }
            #pragma unroll
            for (int i = 0; i < 2; i++) {
                int c = (nt0s + p * 2 + i) * 16 + l16;
                float badd = 0.f;
                if (c >= 128) badd = eb1n[c - 128];
                #pragma unroll
                for (int g = 0; g < 4; g++)
                    #pragma unroll
                    for (int r = 0; r < 4; r++) {
                        int n = n0 + g * 16 + q * 4 + r;
                        if (n < N_NODES) {
                            unsigned short v = f2bf(accs[g][i][r] + badd);
                            if (c < 128) S[n * HID + c] = v;
                            else         D[n * HID + (c - 128)] = v;
                        }
                    }
            }
        }
    } else {
        // decoder: out = new_h @ dec_w + dec_b
        if (t < 64 * NODE_OUT) {
            int nl = t / 3, o = t - 3 * nl;
            int n = n0 + nl;
            if (n < N_NODES) {
                float a = db[o];
                #pragma unroll 4
                for (int k = 0; k < HID; k++) a += bf2f(in_h[nl][k]) * dw[k * 3 + o];
                out[n * 3 + o] = a;
            }
        }
    }
}

extern "C" void kernel_launch(void* const* d_in, const int* in_sizes, int n_in,
                              void* d_out, int out_size, void* d_ws, size_t ws_size,
                              hipStream_t stream) {
    const float* x       = (const float*)d_in[0];
    const int*   ei      = (const int*)d_in[1];
    const float* enc_w   = (const float*)d_in[2];
    const float* enc_b   = (const float*)d_in[3];
    const float* dec_w   = (const float*)d_in[4];
    const float* dec_b   = (const float*)d_in[5];
    const float* edge_w1 = (const float*)d_in[6];
    const float* edge_b1 = (const float*)d_in[7];
    const float* edge_w2 = (const float*)d_in[8];
    const float* edge_b2 = (const float*)d_in[9];
    const float* node_w1 = (const float*)d_in[10];
    const float* node_b1 = (const float*)d_in[11];
    const float* node_w2 = (const float*)d_in[12];
    const float* node_b2 = (const float*)d_in[13];

    char* ws = (char*)d_ws;
    unsigned short* h    = (unsigned short*)ws;                    // 12.8 MB
    float*          aggH = (float*)(ws + 12800000);                // 25.6 MB
    unsigned short* swz  = (unsigned short*)(ws + 38400000);       // 589,824 B
    int* cnt             = (int*)(ws + 38989824);                  // 200,000 B (degrees)
    int* ex              = (int*)(ws + 39189824);                  // 200,000 B
    int* bsums           = (int*)(ws + 39389824);                  // 1,024 B
    int* rsrt            = (int*)(ws + 39390848);                  // 3.2 MB (rows, dest-sorted)
    unsigned short* Sbuf = (unsigned short*)(ws + 45790848);       // 12.8 MB
    unsigned short* Dbuf = (unsigned short*)(ws + 58590848);       // 12.8 MB
    float* Mtmp          = (float*)(ws + 71390848);                // 196,608 B
    float* Vtmp          = (float*)(ws + 71587456);                // 1,536 B
    int* ex2             = (int*)(ws + 71588992);                  // 200,000 B -> end 71,788,992
    // rank overlays the Dbuf region: written in k1, consumed in k3a,
    // before Dbuf's first write in k3b. No extra workspace.
    int* rank            = (int*)(ws + 58590848);                  // 3.2 MB (aliases Dbuf)

    const int* rowp = ei;            // edge_index[0] = source
    const int* colp = ei + N_EDGES;  // edge_index[1] = destination

    hipMemsetAsync(cnt, 0, (size_t)N_NODES * 4, stream);

    k1_hist_mfold<<<EDGE_BLOCKS + MFOLD_BLOCKS, 256, 0, stream>>>(
        colp, cnt, rank, edge_w2, node_w1, edge_b2, Mtmp, Vtmp);
    k2a_scan1_swizzle<<<SCAN_BLOCKS + 288, 256, 0, stream>>>(cnt, ex, bsums, edge_w1,
                                                             node_w1, node_w2, Mtmp, swz);
    k3a_scatter<<<3125, 256, 0, stream>>>(rowp, colp, ex, bsums, rank, rsrt, ex2);
    k3b_encoder_sd<<<NODE_TILES, 256, 0, stream>>>(x, enc_w, enc_b, swz /*L0 w1cat*/,
                                                   edge_b1 /*fold L0 bias into D*/, h,
                                                   Sbuf, Dbuf);

    for (int L = 0; L < 3; L++) {
        unsigned short* base = swz + (size_t)L * 98304;
        unsigned short* next = swz + (size_t)(L + 1) * 98304;   // w1cat of next layer
        edge_kernel<<<1568, 256, 0, stream>>>(Sbuf, Dbuf, rsrt, ex2, aggH);
        if (L < 2) {
            node_kernel<0><<<NODE_TILES, 256, 0, stream>>>(
                h, aggH, cnt,
                base + 49152, node_b1 + (size_t)L * HID, Vtmp + (size_t)L * HID,
                base + 81920, node_b2 + (size_t)L * HID,
                next, edge_b1 + (size_t)(L + 1) * HID, Sbuf, Dbuf, dec_w, dec_b, (float*)d_out);
        } else {
            node_kernel<1><<<NODE_TILES, 256, 0, stream>>>(
                h, aggH, cnt,
                base + 49152, node_b1 + (size_t)L * HID, Vtmp + (size_t)L * HID,
                base + 81920, node_b2 + (size_t)L * HID,
                base /*unused*/, edge_b1 /*unused*/, Sbuf, Dbuf, dec_w, dec_b, (float*)d_out);
        }
    }
}

// Round 6
// 364.916 us; speedup vs baseline: 1.6957x; 1.0557x over previous
//
#include <hip/hip_runtime.h>
#include <hip/hip_bf16.h>
#include <stdint.h>

#define N_NODES 50000
#define N_EDGES 800000
#define HID 128
#define NODE_IN 16
#define NODE_OUT 3
#define NODE_TILES 782     // ceil(50000 / 64)
#define SCAN_BLOCKS 196    // ceil(50000 / 256)
#define EDGE_BLOCKS 3125   // 800000 / 256, one edge per thread in k1
#define MFOLD_BLOCKS 192   // 3*16384 / 256
#define DGB 16             // dests per edge-kernel block (16 groups x 1)
#define EDBLOCKS 3125      // 50000 / 16, exact

typedef __attribute__((ext_vector_type(8))) short short8;
typedef __attribute__((ext_vector_type(4))) float f32x4;
typedef __attribute__((ext_vector_type(4))) unsigned int u32x4;

__device__ __forceinline__ unsigned short f2bf(float f) {
    union { float f; unsigned int u; } v; v.f = f;
    unsigned int u = v.u;
    u += 0x7fff + ((u >> 16) & 1);   // round-to-nearest-even
    return (unsigned short)(u >> 16);
}
__device__ __forceinline__ float bf2f(unsigned short s) {
    union { unsigned int u; float f; } v; v.u = ((unsigned int)s) << 16;
    return v.f;
}
__device__ __forceinline__ float bfu_lo(unsigned int u) {
    union { unsigned int u; float f; } v; v.u = u << 16; return v.f;
}
__device__ __forceinline__ float bfu_hi(unsigned int u) {
    union { unsigned int u; float f; } v; v.u = u & 0xffff0000u; return v.f;
}
// 2x f32 -> packed bf16 (RNE), single HW instruction on gfx950
__device__ __forceinline__ unsigned int cvt_pk_bf16(float lo, float hi) {
    unsigned int r;
    asm("v_cvt_pk_bf16_f32 %0, %1, %2" : "=v"(r) : "v"(lo), "v"(hi));
    return r;
}

// ---------------- K1: hist (+rank) || M-fold || encoder ----------------
// Hist blocks saturate the atomic-RMW pipe at ~0.9% VALU (structural ceiling,
// proven R3->R4: occupancy doubling changed nothing). Encoder and M-fold are
// independent of cnt/rank -> run them as tail blocks, hidden under the atomics.
__global__ __launch_bounds__(256) void k1_fused(
    const int* __restrict__ colp, int* __restrict__ cnt, int* __restrict__ rank,
    const float* __restrict__ edge_w2, const float* __restrict__ node_w1,
    const float* __restrict__ edge_b2,
    float* __restrict__ Mtmp, float* __restrict__ Vtmp,
    const float* __restrict__ x, const float* __restrict__ enc_w,
    const float* __restrict__ enc_b, unsigned short* __restrict__ h) {
    __shared__ float wts[NODE_IN * HID];
    __shared__ float bts[HID];
    __shared__ float xs[64][NODE_IN];
    int b = blockIdx.x, t = threadIdx.x;
    if (b < EDGE_BLOCKS) {
        int e = b * 256 + t;   // exact: 3125*256 = 800000
        rank[e] = atomicAdd(&cnt[colp[e]], 1);   // old value = within-dest rank
    } else if (b < EDGE_BLOCKS + MFOLD_BLOCKS) {
        int d = (b - EDGE_BLOCKS) * 256 + t;     // exact: 192*256 = 49152 = 3*16384
        int L = d / 16384, rem = d & 16383;
        int k = rem >> 7, n = rem & 127;
        const float* w2  = edge_w2 + (size_t)L * 16384;
        const float* w1b = node_w1 + (size_t)L * 32768 + 16384;   // bottom-half rows
        float acc = 0.f;
        #pragma unroll 4
        for (int j = 0; j < 128; j++) acc += w2[k * 128 + j] * w1b[j * 128 + n];
        Mtmp[d] = acc;
        if (k == 0) {
            const float* b2 = edge_b2 + (size_t)L * 128;
            float vv = 0.f;
            #pragma unroll 4
            for (int j = 0; j < 128; j++) vv += b2[j] * w1b[j * 128 + n];
            Vtmp[L * 128 + n] = vv;
        }
    } else {
        // encoder: h = x @ enc_w + enc_b (bf16 store)
        int b2 = b - EDGE_BLOCKS - MFOLD_BLOCKS;   // 0..781
        int n0 = b2 * 64;
        for (int i = t; i < NODE_IN * HID; i += 256) wts[i] = enc_w[i];
        if (t < HID) bts[t] = enc_b[t];
        for (int i = t; i < 64 * NODE_IN; i += 256) {
            int nl = i >> 4, ii = i & 15;
            int n = n0 + nl;
            xs[nl][ii] = (n < N_NODES) ? x[n * NODE_IN + ii] : 0.f;
        }
        __syncthreads();
        for (int o = t; o < 64 * HID; o += 256) {
            int nl = o >> 7, cc = o & 127;
            float acc = bts[cc];
            #pragma unroll
            for (int i = 0; i < NODE_IN; i++) acc += xs[nl][i] * wts[i * HID + cc];
            int n = n0 + nl;
            if (n < N_NODES) h[n * HID + cc] = f2bf(acc);
        }
    }
}

// ---------------- K2a: parallel scan1 (blocks < SCAN_BLOCKS) + weight swizzles ----------------
// swz per-layer layout: +0 edge w1cat (32768), [32768..49152) unused,
//                       +49152 node w1-modified [W1top; M] (32768), +81920 node w2 (16384)
__global__ __launch_bounds__(256) void k2a_scan1_swizzle(
    const int* __restrict__ cnt, int* __restrict__ ex, int* __restrict__ bsums,
    const float* __restrict__ edge_w1, const float* __restrict__ node_w1,
    const float* __restrict__ node_w2, const float* __restrict__ Mtmp,
    unsigned short* __restrict__ swz) {
    __shared__ int s[256];
    int b = blockIdx.x, t = threadIdx.x;
    if (b < SCAN_BLOCKS) {
        int i = b * 256 + t;
        int v = (i < N_NODES) ? cnt[i] : 0;
        s[t] = v;
        __syncthreads();
        for (int off = 1; off < 256; off <<= 1) {
            int u = (t >= off) ? s[t - off] : 0;
            __syncthreads();
            s[t] += u;
            __syncthreads();
        }
        if (i < N_NODES) ex[i] = s[t] - v;
        if (t == 255) bsums[b] = s[255];
    } else {
        for (int d = (b - SCAN_BLOCKS) * 256 + t; d < 3 * 98304;
             d += (gridDim.x - SCAN_BLOCKS) * 256) {
            int L = d / 98304;
            int rem = d - L * 98304;
            unsigned short* base = swz + L * 98304;
            if (rem < 32768) {
                // edge w1 combined [128 x 256] B-frags (16 n-tiles)
                const float* w1 = edge_w1 + (size_t)L * 32768;
                int j = rem & 7, ll = (rem >> 3) & 63, tt = rem >> 9;
                int nt = tt & 15, kt = tt >> 4;
                int k = kt * 32 + ((ll >> 4) << 3) + j;
                int cc = nt * 16 + (ll & 15);
                float v = (cc < 128) ? w1[k * 128 + cc] : w1[(128 + k) * 128 + (cc - 128)];
                base[rem] = f2bf(v);
            } else if (rem < 49152) {
                // unused slot (edge w2 folded into node w1 via M)
            } else if (rem < 81920) {
                int d2 = rem - 49152;
                int j = d2 & 7, ll = (d2 >> 3) & 63, tt = d2 >> 9;
                int nt = tt & 7, kt = tt >> 3;
                int k = kt * 32 + ((ll >> 4) << 3) + j, n = (nt << 4) + (ll & 15);
                float v = (k < 128) ? node_w1[(size_t)L * 32768 + k * 128 + n]
                                    : Mtmp[(size_t)L * 16384 + (k - 128) * 128 + n];
                base[rem] = f2bf(v);
            } else {
                int d2 = rem - 81920;
                const float* src = node_w2 + (size_t)L * 16384;
                int j = d2 & 7, ll = (d2 >> 3) & 63, tt = d2 >> 9;
                int nt = tt & 7, kt = tt >> 3;
                int k = kt * 32 + ((ll >> 4) << 3) + j, n = (nt << 4) + (ll & 15);
                base[rem] = f2bf(src[k * 128 + n]);
            }
        }
    }
}

// ---------------- K3: scatter (+ex2) || S/D layer-0 generation ----------------
// Scatter blocks (memory/atomic-free) and S/D MFMA blocks (compute) overlap.
__global__ __launch_bounds__(256) void k3_scatter_sd(
    const int* __restrict__ rowp, const int* __restrict__ colp,
    const int* __restrict__ ex, const int* __restrict__ bsums,
    const int* __restrict__ rank, int* __restrict__ rsrt, int* __restrict__ ex2,
    const unsigned short* __restrict__ h, const unsigned short* __restrict__ w1c,
    const float* __restrict__ eb1,
    unsigned short* __restrict__ S, unsigned short* __restrict__ D) {
    __shared__ int sc[256];
    __shared__ int ls[SCAN_BLOCKS];
    __shared__ unsigned short hs[64][136];
    int b = blockIdx.x, t = threadIdx.x;
    if (b < EDGE_BLOCKS) {
        // redundant per-block exclusive scan of the 196 block sums
        int v = (t < SCAN_BLOCKS) ? bsums[t] : 0;
        sc[t] = v;
        __syncthreads();
        for (int off = 1; off < 256; off <<= 1) {
            int u = (t >= off) ? sc[t - off] : 0;
            __syncthreads();
            sc[t] += u;
            __syncthreads();
        }
        if (t < SCAN_BLOCKS) ls[t] = sc[t] - v;
        __syncthreads();

        // global exclusive segment starts (consumed by ownership edge_kernel)
        if (b < SCAN_BLOCKS) {
            int i = b * 256 + t;
            if (i < N_NODES) ex2[i] = ex[i] + ls[b];
        }
        int e = b * 256 + t;   // exact 800000
        int c = colp[e];
        int pos = ex[c] + ls[c >> 8] + rank[e];
        rsrt[pos] = rowp[e];   // dest implied by position
    } else {
        // S/D for layer 0 from h (D gets +edge_b1[0] folded)
        int b2 = b - EDGE_BLOCKS;   // 0..781
        int wave = t >> 6, l = t & 63, q = l >> 4, l16 = l & 15;
        int nt0s = wave * 4;
        int n0 = b2 * 64;
        for (int i = t; i < 64 * 16; i += 256) {
            int nl = i >> 4, li = i & 15;
            int n = n0 + nl;
            short8 v = (short8){0, 0, 0, 0, 0, 0, 0, 0};
            if (n < N_NODES) v = *(const short8*)(h + (size_t)n * HID + li * 8);
            *(short8*)&hs[nl][li * 8] = v;
        }
        short8 wr[4][4];
        #pragma unroll
        for (int kt = 0; kt < 4; kt++)
            #pragma unroll
            for (int i = 0; i < 4; i++)
                wr[kt][i] = *(const short8*)(w1c + ((kt * 16 + nt0s + i) * 64 + l) * 8);
        __syncthreads();

        f32x4 acc[4][4];
        #pragma unroll
        for (int g = 0; g < 4; g++)
            #pragma unroll
            for (int i = 0; i < 4; i++) acc[g][i] = (f32x4){0.f, 0.f, 0.f, 0.f};
        #pragma unroll
        for (int kt = 0; kt < 4; kt++) {
            #pragma unroll
            for (int g = 0; g < 4; g++) {
                short8 a = *(const short8*)&hs[g * 16 + l16][kt * 32 + q * 8];
                #pragma unroll
                for (int i = 0; i < 4; i++)
                    acc[g][i] = __builtin_amdgcn_mfma_f32_16x16x32_bf16(a, wr[kt][i], acc[g][i], 0, 0, 0);
            }
        }
        #pragma unroll
        for (int i = 0; i < 4; i++) {
            int cc = (nt0s + i) * 16 + l16;
            float badd = 0.f;
            if (cc >= 128) badd = eb1[cc - 128];   // fold edge_b1[L=0] into D
            #pragma unroll
            for (int g = 0; g < 4; g++)
                #pragma unroll
                for (int r = 0; r < 4; r++) {
                    int n = n0 + g * 16 + q * 4 + r;
                    if (n < N_NODES) {
                        unsigned short v = f2bf(acc[g][i][r] + badd);
                        if (cc < 128) S[n * HID + cc] = v;
                        else          D[n * HID + (cc - 128)] = v;
                    }
                }
        }
    }
}

// ---------------- edge: register-accumulating dest-ownership, depth-2 prefetch ----------------
// 16-lane group (8 ch/lane = 128 ch) owns ONE dest: shorter serial chain (~16)
// than R5's 2-dest walk (~32), less intra-wave divergence, and two S-row loads
// in flight. No LDS / barriers / atomics. aggH fully written -> no zeroing.
__global__ __launch_bounds__(256, 8) void edge_kernel(
    const unsigned short* __restrict__ S, const unsigned short* __restrict__ D,
    const int* __restrict__ rsrt, const int* __restrict__ ex2,
    float* __restrict__ aggH)
{
    int t = threadIdx.x;
    int g16 = t >> 4, ch = t & 15;

    // XCD-chunked bijective mapping over EDBLOCKS dest-blocks
    const int q = EDBLOCKS / 8, r = EDBLOCKS % 8;   // 390, 5
    int xcd = blockIdx.x & 7, slot = blockIdx.x >> 3;
    int cntx = q + (xcd < r);
    if (slot >= cntx) return;
    int myb = xcd * q + (xcd < r ? xcd : r) + slot;

    int d = myb * DGB + g16;   // exact: 3125*16 = 50000, always < N_NODES
    int e0 = ex2[d];
    int e1 = (d < N_NODES - 1) ? ex2[d + 1] : N_EDGES;

    // D row slice once per dest (b1 folded in)
    short8 dv = *(const short8*)(D + (size_t)d * HID + ch * 8);
    float dr[8];
    #pragma unroll
    for (int p = 0; p < 4; p++) {
        unsigned int ud = ((const unsigned int*)&dv)[p];
        dr[2 * p]     = bfu_lo(ud);
        dr[2 * p + 1] = bfu_hi(ud);
    }

    float a[8];
    #pragma unroll
    for (int j = 0; j < 8; j++) a[j] = 0.f;

    auto ldS = [&](int e) -> short8 {
        int rn = rsrt[e];
        return *(const short8*)(S + (size_t)rn * HID + ch * 8);
    };
    auto accum = [&](const short8& sv) {
        #pragma unroll
        for (int p = 0; p < 4; p++) {
            unsigned int us = ((const unsigned int*)&sv)[p];
            float v0 = bfu_lo(us) + dr[2 * p];
            float v1 = bfu_hi(us) + dr[2 * p + 1];
            v0 = v0 > 0.f ? v0 : 0.f;
            v1 = v1 > 0.f ? v1 : 0.f;
            a[2 * p]     += v0;
            a[2 * p + 1] += v1;
        }
    };

    int e = e0;
    short8 s0 = (short8){0, 0, 0, 0, 0, 0, 0, 0};
    short8 s1 = s0;
    if (e < e1)     s0 = ldS(e);
    if (e + 1 < e1) s1 = ldS(e + 1);
    for (; e + 2 < e1; e += 2) {
        short8 n0v = ldS(e + 2);
        short8 n1v = (e + 3 < e1) ? ldS(e + 3) : (short8){0, 0, 0, 0, 0, 0, 0, 0};
        accum(s0);
        accum(s1);
        s0 = n0v;
        s1 = n1v;
    }
    if (e < e1)     accum(s0);
    if (e + 1 < e1) accum(s1);

    f32x4* dst = (f32x4*)(aggH + (size_t)d * HID + ch * 8);
    dst[0] = (f32x4){a[0], a[1], a[2], a[3]};
    dst[1] = (f32x4){a[4], a[5], a[6], a[7]};
}

// ---------------- node MLP (folded GEMM1) + residual + (next S/D | decoder) ----------------
template<int LAST>
__global__ __launch_bounds__(256, 4) void node_kernel(
    unsigned short* __restrict__ h, float* __restrict__ aggH, const int* __restrict__ cnt,
    const unsigned short* __restrict__ w1m_s, const float* __restrict__ b1,
    const float* __restrict__ vfold,
    const unsigned short* __restrict__ w2s, const float* __restrict__ b2,
    const unsigned short* __restrict__ w1c_next, const float* __restrict__ eb1n,
    unsigned short* __restrict__ S, unsigned short* __restrict__ D,
    const float* __restrict__ dec_w, const float* __restrict__ dec_b, float* __restrict__ out)
{
    __shared__ unsigned short in_h[64][136];   // old h -> new h after residual
    __shared__ unsigned short in_a[64][136];   // bf16(aggH); reused as hid after GEMM1
    __shared__ int cnt_s[64];
    __shared__ float dw[HID * NODE_OUT];
    __shared__ float db[NODE_OUT];
    int t = threadIdx.x, wave = t >> 6, l = t & 63, q = l >> 4, l16 = l & 15;
    int nt0 = wave * 2, nt0s = wave * 4;
    int n0 = blockIdx.x * 64;

    if (LAST) {
        for (int i = t; i < HID * NODE_OUT; i += 256) dw[i] = dec_w[i];
        if (t < NODE_OUT) db[t] = dec_b[t];
    }

    // stage: h -> in_h, bf16(aggH) -> in_a (no re-zero: edge_kernel overwrites), cnt
    #pragma unroll
    for (int it = 0; it < 8; it++) {
        int g = it * 256 + t;
        int nl = g >> 5, sub = g & 31, half = sub >> 4, li = sub & 15;
        int n = n0 + nl;
        short8 v = (short8){0, 0, 0, 0, 0, 0, 0, 0};
        if (n < N_NODES) {
            if (half == 0) {
                v = *(const short8*)(h + n * HID + li * 8);
            } else {
                const float* ap = aggH + n * HID + li * 8;
                f32x4 a0 = *(const f32x4*)ap, a1 = *(const f32x4*)(ap + 4);
                unsigned int* vp = (unsigned int*)&v;
                vp[0] = cvt_pk_bf16(a0[0], a0[1]);
                vp[1] = cvt_pk_bf16(a0[2], a0[3]);
                vp[2] = cvt_pk_bf16(a1[0], a1[1]);
                vp[3] = cvt_pk_bf16(a1[2], a1[3]);
            }
        }
        if (half == 0) *(short8*)&in_h[nl][li * 8] = v;
        else           *(short8*)&in_a[nl][li * 8] = v;
    }
    if (t < 64) cnt_s[t] = (n0 + t < N_NODES) ? cnt[n0 + t] : 0;
    __syncthreads();

    float b1r0 = b1[nt0 * 16 + l16], b1r1 = b1[(nt0 + 1) * 16 + l16];
    float vr0 = vfold[nt0 * 16 + l16], vr1 = vfold[(nt0 + 1) * 16 + l16];
    float b2r0 = b2[nt0 * 16 + l16], b2r1 = b2[(nt0 + 1) * 16 + l16];

    // GEMM1 (K=256, B = [W1top; M] folded): h@W1top + aggH@M
    f32x4 acc[4][2];
    #pragma unroll
    for (int g = 0; g < 4; g++)
        #pragma unroll
        for (int j = 0; j < 2; j++) acc[g][j] = (f32x4){0.f, 0.f, 0.f, 0.f};
    #pragma unroll
    for (int kt = 0; kt < 8; kt++) {
        short8 b0 = *(const short8*)(w1m_s + ((kt * 8 + nt0)     * 64 + l) * 8);
        short8 b1v = *(const short8*)(w1m_s + ((kt * 8 + nt0 + 1) * 64 + l) * 8);
        #pragma unroll
        for (int g = 0; g < 4; g++) {
            short8 a = (kt < 4) ? *(const short8*)&in_h[g * 16 + l16][kt * 32 + q * 8]
                                : *(const short8*)&in_a[g * 16 + l16][(kt - 4) * 32 + q * 8];
            acc[g][0] = __builtin_amdgcn_mfma_f32_16x16x32_bf16(a, b0, acc[g][0], 0, 0, 0);
            acc[g][1] = __builtin_amdgcn_mfma_f32_16x16x32_bf16(a, b1v, acc[g][1], 0, 0, 0);
        }
    }
    __syncthreads();   // all in_a reads complete before hid overwrite

    // epilogue: + b1 + deg*v -> relu -> hid (aliases in_a)
    #pragma unroll
    for (int j = 0; j < 2; j++) {
        float bv = j ? b1r1 : b1r0;
        float vv = j ? vr1 : vr0;
        #pragma unroll
        for (int g = 0; g < 4; g++)
            #pragma unroll
            for (int r = 0; r < 4; r++) {
                int m2 = g * 16 + q * 4 + r;
                float v = acc[g][j][r] + bv + (float)cnt_s[m2] * vv;
                v = v > 0.f ? v : 0.f;
                in_a[m2][(nt0 + j) * 16 + l16] = f2bf(v);
            }
    }
    __syncthreads();

    // GEMM2n (K=128) -> residual -> h + in_h
    f32x4 acc2[4][2];
    #pragma unroll
    for (int g = 0; g < 4; g++)
        #pragma unroll
        for (int j = 0; j < 2; j++) acc2[g][j] = (f32x4){0.f, 0.f, 0.f, 0.f};
    #pragma unroll
    for (int kt = 0; kt < 4; kt++) {
        short8 b0 = *(const short8*)(w2s + ((kt * 8 + nt0)     * 64 + l) * 8);
        short8 b1v = *(const short8*)(w2s + ((kt * 8 + nt0 + 1) * 64 + l) * 8);
        #pragma unroll
        for (int g = 0; g < 4; g++) {
            short8 a = *(const short8*)&in_a[g * 16 + l16][kt * 32 + q * 8];
            acc2[g][0] = __builtin_amdgcn_mfma_f32_16x16x32_bf16(a, b0, acc2[g][0], 0, 0, 0);
            acc2[g][1] = __builtin_amdgcn_mfma_f32_16x16x32_bf16(a, b1v, acc2[g][1], 0, 0, 0);
        }
    }
    #pragma unroll
    for (int j = 0; j < 2; j++) {
        float bv = j ? b2r1 : b2r0;
        #pragma unroll
        for (int g = 0; g < 4; g++)
            #pragma unroll
            for (int r = 0; r < 4; r++) {
                float v = acc2[g][j][r] + bv;
                int m2 = g * 16 + q * 4 + r;
                int n = n0 + m2;
                if (n < N_NODES) {
                    int c = (nt0 + j) * 16 + l16;
                    unsigned short nh = f2bf(bf2f(in_h[m2][c]) + v);   // residual (same-thread cell)
                    if (!LAST) h[n * HID + c] = nh;
                    in_h[m2][c] = nh;
                }
            }
    }
    __syncthreads();

    if (!LAST) {
        // next-layer S/D from new h (in_h), in 2 register-light passes
        // D gets +edge_b1[L+1] folded so edge_kernel skips the bias add
        #pragma unroll
        for (int p = 0; p < 2; p++) {
            short8 wr[4][2];
            #pragma unroll
            for (int kt = 0; kt < 4; kt++) {
                wr[kt][0] = *(const short8*)(w1c_next + ((kt * 16 + nt0s + p * 2)     * 64 + l) * 8);
                wr[kt][1] = *(const short8*)(w1c_next + ((kt * 16 + nt0s + p * 2 + 1) * 64 + l) * 8);
            }
            f32x4 accs[4][2];
            #pragma unroll
            for (int g = 0; g < 4; g++)
                #pragma unroll
                for (int i = 0; i < 2; i++) accs[g][i] = (f32x4){0.f, 0.f, 0.f, 0.f};
            #pragma unroll
            for (int kt = 0; kt < 4; kt++) {
                #pragma unroll
                for (int g = 0; g < 4; g++) {
                    short8 a = *(const short8*)&in_h[g * 16 + l16][kt * 32 + q * 8];
                    accs[g][0] = __builtin_amdgcn_mfma_f32_16x16x32_bf16(a, wr[kt][0], accs[g][0], 0, 0, 0);
                    accs[g][1] = __builtin_amdgcn_mfma_f32_16x16x32_bf16(a, wr[kt][1], accs[g][1], 0, 0, 0);
                }
            }
            #pragma unroll
            for (int i = 0; i < 2; i++) {
                int c = (nt0s + p * 2 + i) * 16 + l16;
                float badd = 0.f;
                if (c >= 128) badd = eb1n[c - 128];
                #pragma unroll
                for (int g = 0; g < 4; g++)
                    #pragma unroll
                    for (int r = 0; r < 4; r++) {
                        int n = n0 + g * 16 + q * 4 + r;
                        if (n < N_NODES) {
                            unsigned short v = f2bf(accs[g][i][r] + badd);
                            if (c < 128) S[n * HID + c] = v;
                            else         D[n * HID + (c - 128)] = v;
                        }
                    }
            }
        }
    } else {
        // decoder: out = new_h @ dec_w + dec_b
        if (t < 64 * NODE_OUT) {
            int nl = t / 3, o = t - 3 * nl;
            int n = n0 + nl;
            if (n < N_NODES) {
                float a = db[o];
                #pragma unroll 4
                for (int k = 0; k < HID; k++) a += bf2f(in_h[nl][k]) * dw[k * 3 + o];
                out[n * 3 + o] = a;
            }
        }
    }
}

extern "C" void kernel_launch(void* const* d_in, const int* in_sizes, int n_in,
                              void* d_out, int out_size, void* d_ws, size_t ws_size,
                              hipStream_t stream) {
    const float* x       = (const float*)d_in[0];
    const int*   ei      = (const int*)d_in[1];
    const float* enc_w   = (const float*)d_in[2];
    const float* enc_b   = (const float*)d_in[3];
    const float* dec_w   = (const float*)d_in[4];
    const float* dec_b   = (const float*)d_in[5];
    const float* edge_w1 = (const float*)d_in[6];
    const float* edge_b1 = (const float*)d_in[7];
    const float* edge_w2 = (const float*)d_in[8];
    const float* edge_b2 = (const float*)d_in[9];
    const float* node_w1 = (const float*)d_in[10];
    const float* node_b1 = (const float*)d_in[11];
    const float* node_w2 = (const float*)d_in[12];
    const float* node_b2 = (const float*)d_in[13];

    char* ws = (char*)d_ws;
    unsigned short* h    = (unsigned short*)ws;                    // 12.8 MB
    float*          aggH = (float*)(ws + 12800000);                // 25.6 MB
    unsigned short* swz  = (unsigned short*)(ws + 38400000);       // 589,824 B
    int* cnt             = (int*)(ws + 38989824);                  // 200,000 B (degrees)
    int* ex              = (int*)(ws + 39189824);                  // 200,000 B
    int* bsums           = (int*)(ws + 39389824);                  // 1,024 B
    int* rsrt            = (int*)(ws + 39390848);                  // 3.2 MB (rows, dest-sorted)
    unsigned short* Sbuf = (unsigned short*)(ws + 45790848);       // 12.8 MB
    unsigned short* Dbuf = (unsigned short*)(ws + 58590848);       // 12.8 MB
    float* Mtmp          = (float*)(ws + 71390848);                // 196,608 B
    float* Vtmp          = (float*)(ws + 71587456);                // 1,536 B
    int* ex2             = (int*)(ws + 71588992);                  // 200,000 B
    int* rank            = (int*)(ws + 72000000);                  // 3.2 MB (own slot:
                                                                   // no longer aliases Dbuf —
                                                                   // k3 reads rank & writes D)

    const int* rowp = ei;            // edge_index[0] = source
    const int* colp = ei + N_EDGES;  // edge_index[1] = destination

    hipMemsetAsync(cnt, 0, (size_t)N_NODES * 4, stream);

    k1_fused<<<EDGE_BLOCKS + MFOLD_BLOCKS + NODE_TILES, 256, 0, stream>>>(
        colp, cnt, rank, edge_w2, node_w1, edge_b2, Mtmp, Vtmp,
        x, enc_w, enc_b, h);
    k2a_scan1_swizzle<<<SCAN_BLOCKS + 288, 256, 0, stream>>>(cnt, ex, bsums, edge_w1,
                                                             node_w1, node_w2, Mtmp, swz);
    k3_scatter_sd<<<EDGE_BLOCKS + NODE_TILES, 256, 0, stream>>>(
        rowp, colp, ex, bsums, rank, rsrt, ex2,
        h, swz /*L0 w1cat*/, edge_b1 /*fold L0 bias into D*/, Sbuf, Dbuf);

    for (int L = 0; L < 3; L++) {
        unsigned short* base = swz + (size_t)L * 98304;
        unsigned short* next = swz + (size_t)(L + 1) * 98304;   // w1cat of next layer
        edge_kernel<<<3128, 256, 0, stream>>>(Sbuf, Dbuf, rsrt, ex2, aggH);
        if (L < 2) {
            node_kernel<0><<<NODE_TILES, 256, 0, stream>>>(
                h, aggH, cnt,
                base + 49152, node_b1 + (size_t)L * HID, Vtmp + (size_t)L * HID,
                base + 81920, node_b2 + (size_t)L * HID,
                next, edge_b1 + (size_t)(L + 1) * HID, Sbuf, Dbuf, dec_w, dec_b, (float*)d_out);
        } else {
            node_kernel<1><<<NODE_TILES, 256, 0, stream>>>(
                h, aggH, cnt,
                base + 49152, node_b1 + (size_t)L * HID, Vtmp + (size_t)L * HID,
                base + 81920, node_b2 + (size_t)L * HID,
                base /*unused*/, edge_b1 /*unused*/, Sbuf, Dbuf, dec_w, dec_b, (float*)d_out);
        }
    }
}

// Round 7
// 364.561 us; speedup vs baseline: 1.6973x; 1.0010x over previous
//
#include <hip/hip_runtime.h>
#include <hip/hip_bf16.h>
#include <stdint.h>

#define N_NODES 50000
#define N_EDGES 800000
#define HID 128
#define NODE_IN 16
#define NODE_OUT 3
#define NODE_TILES 782     // ceil(50000 / 64)
#define SCAN_BLOCKS 196    // ceil(50000 / 256)
#define EDGE_BLOCKS 3125   // 800000 / 256, one edge per thread in k1
#define MFOLD_BLOCKS 192   // 3*16384 / 256
#define SWZA_BLOCKS 576    // 3*(32768+16384) / 256  (Mtmp-independent swizzles)
#define SWZB_BLOCKS 384    // 3*32768 / 256          (w1m, Mtmp-dependent)

typedef __attribute__((ext_vector_type(8))) short short8;
typedef __attribute__((ext_vector_type(4))) float f32x4;
typedef __attribute__((ext_vector_type(4))) unsigned int u32x4;

__device__ __forceinline__ unsigned short f2bf(float f) {
    union { float f; unsigned int u; } v; v.f = f;
    unsigned int u = v.u;
    u += 0x7fff + ((u >> 16) & 1);   // round-to-nearest-even
    return (unsigned short)(u >> 16);
}
__device__ __forceinline__ float bf2f(unsigned short s) {
    union { unsigned int u; float f; } v; v.u = ((unsigned int)s) << 16;
    return v.f;
}
__device__ __forceinline__ float bfu_lo(unsigned int u) {
    union { unsigned int u; float f; } v; v.u = u << 16; return v.f;
}
__device__ __forceinline__ float bfu_hi(unsigned int u) {
    union { unsigned int u; float f; } v; v.u = u & 0xffff0000u; return v.f;
}
// 2x f32 -> packed bf16 (RNE), single HW instruction on gfx950
__device__ __forceinline__ unsigned int cvt_pk_bf16(float lo, float hi) {
    unsigned int r;
    asm("v_cvt_pk_bf16_f32 %0, %1, %2" : "=v"(r) : "v"(lo), "v"(hi));
    return r;
}

// ---------------- K1: hist (+rank) || M-fold || encoder || Mtmp-independent swizzles ----------------
// Hist blocks pin the atomic-RMW pipe (~49us structural, VALU ~1%); everything
// independent of cnt/rank/Mtmp rides under it as tail blocks.
__global__ __launch_bounds__(256) void k1_fused(
    const int* __restrict__ colp, int* __restrict__ cnt, int* __restrict__ rank,
    const float* __restrict__ edge_w2, const float* __restrict__ node_w1,
    const float* __restrict__ edge_b2,
    float* __restrict__ Mtmp, float* __restrict__ Vtmp,
    const float* __restrict__ x, const float* __restrict__ enc_w,
    const float* __restrict__ enc_b, unsigned short* __restrict__ h,
    const float* __restrict__ edge_w1, const float* __restrict__ node_w2,
    unsigned short* __restrict__ swz) {
    __shared__ float wts[NODE_IN * HID];
    __shared__ float bts[HID];
    __shared__ float xs[64][NODE_IN];
    int b = blockIdx.x, t = threadIdx.x;
    if (b < EDGE_BLOCKS) {
        int e = b * 256 + t;   // exact: 3125*256 = 800000
        rank[e] = atomicAdd(&cnt[colp[e]], 1);   // old value = within-dest rank
    } else if (b < EDGE_BLOCKS + MFOLD_BLOCKS) {
        int d = (b - EDGE_BLOCKS) * 256 + t;     // exact: 192*256 = 49152 = 3*16384
        int L = d / 16384, rem = d & 16383;
        int k = rem >> 7, n = rem & 127;
        const float* w2  = edge_w2 + (size_t)L * 16384;
        const float* w1b = node_w1 + (size_t)L * 32768 + 16384;   // bottom-half rows
        float acc = 0.f;
        #pragma unroll 4
        for (int j = 0; j < 128; j++) acc += w2[k * 128 + j] * w1b[j * 128 + n];
        Mtmp[d] = acc;
        if (k == 0) {
            const float* b2 = edge_b2 + (size_t)L * 128;
            float vv = 0.f;
            #pragma unroll 4
            for (int j = 0; j < 128; j++) vv += b2[j] * w1b[j * 128 + n];
            Vtmp[L * 128 + n] = vv;
        }
    } else if (b < EDGE_BLOCKS + MFOLD_BLOCKS + NODE_TILES) {
        // encoder: h = x @ enc_w + enc_b (bf16 store)
        int b2 = b - EDGE_BLOCKS - MFOLD_BLOCKS;   // 0..781
        int n0 = b2 * 64;
        for (int i = t; i < NODE_IN * HID; i += 256) wts[i] = enc_w[i];
        if (t < HID) bts[t] = enc_b[t];
        for (int i = t; i < 64 * NODE_IN; i += 256) {
            int nl = i >> 4, ii = i & 15;
            int n = n0 + nl;
            xs[nl][ii] = (n < N_NODES) ? x[n * NODE_IN + ii] : 0.f;
        }
        __syncthreads();
        for (int o = t; o < 64 * HID; o += 256) {
            int nl = o >> 7, cc = o & 127;
            float acc = bts[cc];
            #pragma unroll
            for (int i = 0; i < NODE_IN; i++) acc += xs[nl][i] * wts[i * HID + cc];
            int n = n0 + nl;
            if (n < N_NODES) h[n * HID + cc] = f2bf(acc);
        }
    } else {
        // Mtmp-independent weight swizzles: edge w1cat + node w2
        int d = (b - EDGE_BLOCKS - MFOLD_BLOCKS - NODE_TILES) * 256 + t;  // < 147456 exact
        int L = d / 49152, rem2 = d - L * 49152;
        unsigned short* base = swz + L * 98304;
        if (rem2 < 32768) {
            // edge w1 combined [128 x 256] B-frags (16 n-tiles)
            const float* w1 = edge_w1 + (size_t)L * 32768;
            int j = rem2 & 7, ll = (rem2 >> 3) & 63, tt = rem2 >> 9;
            int nt = tt & 15, kt = tt >> 4;
            int k = kt * 32 + ((ll >> 4) << 3) + j;
            int cc = nt * 16 + (ll & 15);
            float v = (cc < 128) ? w1[k * 128 + cc] : w1[(128 + k) * 128 + (cc - 128)];
            base[rem2] = f2bf(v);
        } else {
            int d2 = rem2 - 32768;   // [0,16384): node w2
            const float* src = node_w2 + (size_t)L * 16384;
            int j = d2 & 7, ll = (d2 >> 3) & 63, tt = d2 >> 9;
            int nt = tt & 7, kt = tt >> 3;
            int k = kt * 32 + ((ll >> 4) << 3) + j, n = (nt << 4) + (ll & 15);
            base[81920 + d2] = f2bf(src[k * 128 + n]);
        }
    }
}

// ---------------- K2a: parallel scan1 + w1m swizzle (Mtmp-dependent) ----------------
__global__ __launch_bounds__(256) void k2a_scan1_swizzle(
    const int* __restrict__ cnt, int* __restrict__ ex, int* __restrict__ bsums,
    const float* __restrict__ node_w1, const float* __restrict__ Mtmp,
    unsigned short* __restrict__ swz) {
    __shared__ int s[256];
    int b = blockIdx.x, t = threadIdx.x;
    if (b < SCAN_BLOCKS) {
        int i = b * 256 + t;
        int v = (i < N_NODES) ? cnt[i] : 0;
        s[t] = v;
        __syncthreads();
        for (int off = 1; off < 256; off <<= 1) {
            int u = (t >= off) ? s[t - off] : 0;
            __syncthreads();
            s[t] += u;
            __syncthreads();
        }
        if (i < N_NODES) ex[i] = s[t] - v;
        if (t == 255) bsums[b] = s[255];
    } else {
        int d = (b - SCAN_BLOCKS) * 256 + t;   // < 98304 exact
        int L = d / 32768, d2 = d - L * 32768;
        unsigned short* base = swz + L * 98304;
        int j = d2 & 7, ll = (d2 >> 3) & 63, tt = d2 >> 9;
        int nt = tt & 7, kt = tt >> 3;
        int k = kt * 32 + ((ll >> 4) << 3) + j, n = (nt << 4) + (ll & 15);
        float v = (k < 128) ? node_w1[(size_t)L * 32768 + k * 128 + n]
                            : Mtmp[(size_t)L * 16384 + (k - 128) * 128 + n];
        base[49152 + d2] = f2bf(v);
    }
}

// ---------------- K3: scatter (+ex2) || S/D layer-0 generation ----------------
__global__ __launch_bounds__(256) void k3_scatter_sd(
    const int* __restrict__ rowp, const int* __restrict__ colp,
    const int* __restrict__ ex, const int* __restrict__ bsums,
    const int* __restrict__ rank, int* __restrict__ rsrt, int* __restrict__ ex2,
    const unsigned short* __restrict__ h, const unsigned short* __restrict__ w1c,
    const float* __restrict__ eb1,
    unsigned short* __restrict__ S, unsigned short* __restrict__ D) {
    __shared__ int sc[256];
    __shared__ int ls[SCAN_BLOCKS];
    __shared__ unsigned short hs[64][136];
    int b = blockIdx.x, t = threadIdx.x;
    if (b < EDGE_BLOCKS) {
        int v = (t < SCAN_BLOCKS) ? bsums[t] : 0;
        sc[t] = v;
        __syncthreads();
        for (int off = 1; off < 256; off <<= 1) {
            int u = (t >= off) ? sc[t - off] : 0;
            __syncthreads();
            sc[t] += u;
            __syncthreads();
        }
        if (t < SCAN_BLOCKS) ls[t] = sc[t] - v;
        __syncthreads();

        if (b < SCAN_BLOCKS) {
            int i = b * 256 + t;
            if (i < N_NODES) ex2[i] = ex[i] + ls[b];
        }
        int e = b * 256 + t;   // exact 800000
        int c = colp[e];
        int pos = ex[c] + ls[c >> 8] + rank[e];
        rsrt[pos] = rowp[e];   // dest implied by position
    } else {
        // S/D for layer 0 from h (D gets +edge_b1[0] folded)
        int b2 = b - EDGE_BLOCKS;   // 0..781
        int wave = t >> 6, l = t & 63, q = l >> 4, l16 = l & 15;
        int nt0s = wave * 4;
        int n0 = b2 * 64;
        for (int i = t; i < 64 * 16; i += 256) {
            int nl = i >> 4, li = i & 15;
            int n = n0 + nl;
            short8 v = (short8){0, 0, 0, 0, 0, 0, 0, 0};
            if (n < N_NODES) v = *(const short8*)(h + (size_t)n * HID + li * 8);
            *(short8*)&hs[nl][li * 8] = v;
        }
        short8 wr[4][4];
        #pragma unroll
        for (int kt = 0; kt < 4; kt++)
            #pragma unroll
            for (int i = 0; i < 4; i++)
                wr[kt][i] = *(const short8*)(w1c + ((kt * 16 + nt0s + i) * 64 + l) * 8);
        __syncthreads();

        f32x4 acc[4][4];
        #pragma unroll
        for (int g = 0; g < 4; g++)
            #pragma unroll
            for (int i = 0; i < 4; i++) acc[g][i] = (f32x4){0.f, 0.f, 0.f, 0.f};
        #pragma unroll
        for (int kt = 0; kt < 4; kt++) {
            #pragma unroll
            for (int g = 0; g < 4; g++) {
                short8 a = *(const short8*)&hs[g * 16 + l16][kt * 32 + q * 8];
                #pragma unroll
                for (int i = 0; i < 4; i++)
                    acc[g][i] = __builtin_amdgcn_mfma_f32_16x16x32_bf16(a, wr[kt][i], acc[g][i], 0, 0, 0);
            }
        }
        #pragma unroll
        for (int i = 0; i < 4; i++) {
            int cc = (nt0s + i) * 16 + l16;
            float badd = 0.f;
            if (cc >= 128) badd = eb1[cc - 128];
            #pragma unroll
            for (int g = 0; g < 4; g++)
                #pragma unroll
                for (int r = 0; r < 4; r++) {
                    int n = n0 + g * 16 + q * 4 + r;
                    if (n < N_NODES) {
                        unsigned short v = f2bf(acc[g][i][r] + badd);
                        if (cc < 128) S[n * HID + cc] = v;
                        else          D[n * HID + (cc - 128)] = v;
                    }
                }
        }
    }
}

// ---------------- fused layer: edge aggregation (reg) -> node MLP, no aggH ----------------
// Block owns nodes n0..n0+63 (= its dests, exclusive). Phase E: 64 groups x 8
// lanes, one dest each; acc += relu(S[row]+D[d]) in 16 f32 regs (2 independent
// S-loads/edge, depth-2 prefetch); cvt_pk -> bf16 straight into in_a LDS.
// Phase N: 8-wave node MLP (GEMM1 folded, GEMM2, residual, next S/D | decoder).
// Reads {S,D,h} of this layer, writes {Sn,Dn,hn} of next -> double-buffered.
template<int LAST>
__global__ __launch_bounds__(512, 4) void layer_kernel(
    const unsigned short* __restrict__ S, const unsigned short* __restrict__ D,
    const int* __restrict__ rsrt, const int* __restrict__ ex2,
    const unsigned short* __restrict__ h, unsigned short* __restrict__ hn,
    const unsigned short* __restrict__ w1m_s, const float* __restrict__ b1,
    const float* __restrict__ vfold,
    const unsigned short* __restrict__ w2s, const float* __restrict__ b2,
    const unsigned short* __restrict__ w1c_next, const float* __restrict__ eb1n,
    unsigned short* __restrict__ Sn, unsigned short* __restrict__ Dn,
    const float* __restrict__ dec_w, const float* __restrict__ dec_b,
    float* __restrict__ out)
{
    __shared__ unsigned short in_h[64][136];
    __shared__ unsigned short in_a[64][136];
    __shared__ int deg_s[64];
    __shared__ float dw[HID * NODE_OUT];
    __shared__ float db[NODE_OUT];
    int t = threadIdx.x;
    int n0 = blockIdx.x * 64;

    // stage h -> in_h (2 passes of 512 x 16B)
    #pragma unroll
    for (int i = t; i < 64 * 16; i += 512) {
        int nl = i >> 4, li = i & 15;
        int n = n0 + nl;
        short8 v = (short8){0, 0, 0, 0, 0, 0, 0, 0};
        if (n < N_NODES) v = *(const short8*)(h + (size_t)n * HID + li * 8);
        *(short8*)&in_h[nl][li * 8] = v;
    }
    if (LAST) {
        if (t < HID * NODE_OUT) dw[t] = dec_w[t];
        if (t < NODE_OUT) db[t] = dec_b[t];
    }

    // ---- phase E: per-dest register aggregation ----
    {
        int g8 = t >> 3, ch8 = t & 7;   // group 0..63 owns dest n0+g8; lane covers ch8*16..+15
        int d = n0 + g8;
        float a[16];
        #pragma unroll
        for (int j = 0; j < 16; j++) a[j] = 0.f;

        if (d < N_NODES) {
            int e0 = ex2[d];
            int e1 = (d == N_NODES - 1) ? N_EDGES : ex2[d + 1];
            if (ch8 == 0) deg_s[g8] = e1 - e0;

            const unsigned short* drow = D + (size_t)d * HID + ch8 * 16;
            short8 dva = *(const short8*)drow;
            short8 dvb = *(const short8*)(drow + 8);
            float dr[16];
            #pragma unroll
            for (int p = 0; p < 4; p++) {
                unsigned int ua = ((const unsigned int*)&dva)[p];
                unsigned int ub = ((const unsigned int*)&dvb)[p];
                dr[2 * p]         = bfu_lo(ua);
                dr[2 * p + 1]     = bfu_hi(ua);
                dr[8 + 2 * p]     = bfu_lo(ub);
                dr[8 + 2 * p + 1] = bfu_hi(ub);
            }

            auto ldS = [&](int e, short8& va, short8& vb) {
                int rn = rsrt[e];
                const unsigned short* p = S + (size_t)rn * HID + ch8 * 16;
                va = *(const short8*)p;
                vb = *(const short8*)(p + 8);
            };
            auto accum = [&](const short8& va, const short8& vb) {
                #pragma unroll
                for (int p = 0; p < 4; p++) {
                    unsigned int ua = ((const unsigned int*)&va)[p];
                    float v0 = bfu_lo(ua) + dr[2 * p];
                    float v1 = bfu_hi(ua) + dr[2 * p + 1];
                    a[2 * p]     += v0 > 0.f ? v0 : 0.f;
                    a[2 * p + 1] += v1 > 0.f ? v1 : 0.f;
                    unsigned int ub = ((const unsigned int*)&vb)[p];
                    float w0 = bfu_lo(ub) + dr[8 + 2 * p];
                    float w1 = bfu_hi(ub) + dr[8 + 2 * p + 1];
                    a[8 + 2 * p]     += w0 > 0.f ? w0 : 0.f;
                    a[8 + 2 * p + 1] += w1 > 0.f ? w1 : 0.f;
                }
            };

            int e = e0;
            short8 s0a = (short8){0,0,0,0,0,0,0,0}, s0b = s0a, s1a = s0a, s1b = s0a;
            if (e < e1)     ldS(e, s0a, s0b);
            if (e + 1 < e1) ldS(e + 1, s1a, s1b);
            for (; e + 2 < e1; e += 2) {
                short8 p0a, p0b, p1a, p1b;
                ldS(e + 2, p0a, p0b);
                if (e + 3 < e1) ldS(e + 3, p1a, p1b);
                else { p1a = (short8){0,0,0,0,0,0,0,0}; p1b = p1a; }
                accum(s0a, s0b);
                accum(s1a, s1b);
                s0a = p0a; s0b = p0b; s1a = p1a; s1b = p1b;
            }
            if (e < e1)     accum(s0a, s0b);
            if (e + 1 < e1) accum(s1a, s1b);
        } else if (ch8 == 0) {
            deg_s[g8] = 0;
        }

        u32x4 oa, ob;
        #pragma unroll
        for (int p = 0; p < 4; p++) {
            oa[p] = cvt_pk_bf16(a[2 * p], a[2 * p + 1]);
            ob[p] = cvt_pk_bf16(a[8 + 2 * p], a[8 + 2 * p + 1]);
        }
        *(u32x4*)&in_a[g8][ch8 * 16]     = oa;
        *(u32x4*)&in_a[g8][ch8 * 16 + 8] = ob;
    }
    __syncthreads();

    // ---- phase N: node MLP, 8 waves, nt = wave ----
    int wave = t >> 6, l = t & 63, q = l >> 4, l16 = l & 15;
    int nt = wave;
    float b1r = b1[nt * 16 + l16];
    float vr  = vfold[nt * 16 + l16];
    float b2r = b2[nt * 16 + l16];

    // GEMM1 (K=256, B = [W1top; M] folded): h@W1top + agg@M
    f32x4 acc[4];
    #pragma unroll
    for (int g = 0; g < 4; g++) acc[g] = (f32x4){0.f, 0.f, 0.f, 0.f};
    #pragma unroll
    for (int kt = 0; kt < 8; kt++) {
        short8 bfr = *(const short8*)(w1m_s + ((kt * 8 + nt) * 64 + l) * 8);
        #pragma unroll
        for (int g = 0; g < 4; g++) {
            short8 afr = (kt < 4) ? *(const short8*)&in_h[g * 16 + l16][kt * 32 + q * 8]
                                  : *(const short8*)&in_a[g * 16 + l16][(kt - 4) * 32 + q * 8];
            acc[g] = __builtin_amdgcn_mfma_f32_16x16x32_bf16(afr, bfr, acc[g], 0, 0, 0);
        }
    }
    __syncthreads();   // all in_a reads complete before hid overwrite

    // epilogue: + b1 + deg*v -> relu -> hid (aliases in_a)
    #pragma unroll
    for (int g = 0; g < 4; g++)
        #pragma unroll
        for (int r = 0; r < 4; r++) {
            int m2 = g * 16 + q * 4 + r;
            float v = acc[g][r] + b1r + (float)deg_s[m2] * vr;
            v = v > 0.f ? v : 0.f;
            in_a[m2][nt * 16 + l16] = f2bf(v);
        }
    __syncthreads();

    // GEMM2 (K=128) -> residual -> hn + in_h
    f32x4 acc2[4];
    #pragma unroll
    for (int g = 0; g < 4; g++) acc2[g] = (f32x4){0.f, 0.f, 0.f, 0.f};
    #pragma unroll
    for (int kt = 0; kt < 4; kt++) {
        short8 bfr = *(const short8*)(w2s + ((kt * 8 + nt) * 64 + l) * 8);
        #pragma unroll
        for (int g = 0; g < 4; g++) {
            short8 afr = *(const short8*)&in_a[g * 16 + l16][kt * 32 + q * 8];
            acc2[g] = __builtin_amdgcn_mfma_f32_16x16x32_bf16(afr, bfr, acc2[g], 0, 0, 0);
        }
    }
    #pragma unroll
    for (int g = 0; g < 4; g++)
        #pragma unroll
        for (int r = 0; r < 4; r++) {
            int m2 = g * 16 + q * 4 + r;
            int n = n0 + m2;
            if (n < N_NODES) {
                int c = nt * 16 + l16;
                unsigned short nh = f2bf(bf2f(in_h[m2][c]) + acc2[g][r] + b2r);
                if (!LAST) hn[n * HID + c] = nh;
                in_h[m2][c] = nh;
            }
        }
    __syncthreads();

    if (!LAST) {
        // next-layer S/D from new h (in_h): 16 tiles over 8 waves (2 each)
        #pragma unroll
        for (int p = 0; p < 2; p++) {
            int nt16 = wave * 2 + p;
            short8 wr[4];
            #pragma unroll
            for (int kt = 0; kt < 4; kt++)
                wr[kt] = *(const short8*)(w1c_next + ((kt * 16 + nt16) * 64 + l) * 8);
            f32x4 accs[4];
            #pragma unroll
            for (int g = 0; g < 4; g++) accs[g] = (f32x4){0.f, 0.f, 0.f, 0.f};
            #pragma unroll
            for (int kt = 0; kt < 4; kt++) {
                #pragma unroll
                for (int g = 0; g < 4; g++) {
                    short8 afr = *(const short8*)&in_h[g * 16 + l16][kt * 32 + q * 8];
                    accs[g] = __builtin_amdgcn_mfma_f32_16x16x32_bf16(afr, wr[kt], accs[g], 0, 0, 0);
                }
            }
            int c = nt16 * 16 + l16;
            float badd = 0.f;
            if (c >= 128) badd = eb1n[c - 128];
            #pragma unroll
            for (int g = 0; g < 4; g++)
                #pragma unroll
                for (int r = 0; r < 4; r++) {
                    int n = n0 + g * 16 + q * 4 + r;
                    if (n < N_NODES) {
                        unsigned short v = f2bf(accs[g][r] + badd);
                        if (c < 128) Sn[n * HID + c] = v;
                        else         Dn[n * HID + (c - 128)] = v;
                    }
                }
        }
    } else {
        // decoder: out = new_h @ dec_w + dec_b
        if (t < 64 * NODE_OUT) {
            int nl = t / 3, o = t - 3 * nl;
            int n = n0 + nl;
            if (n < N_NODES) {
                float a = db[o];
                #pragma unroll 4
                for (int k = 0; k < HID; k++) a += bf2f(in_h[nl][k]) * dw[k * 3 + o];
                out[n * 3 + o] = a;
            }
        }
    }
}

extern "C" void kernel_launch(void* const* d_in, const int* in_sizes, int n_in,
                              void* d_out, int out_size, void* d_ws, size_t ws_size,
                              hipStream_t stream) {
    const float* x       = (const float*)d_in[0];
    const int*   ei      = (const int*)d_in[1];
    const float* enc_w   = (const float*)d_in[2];
    const float* enc_b   = (const float*)d_in[3];
    const float* dec_w   = (const float*)d_in[4];
    const float* dec_b   = (const float*)d_in[5];
    const float* edge_w1 = (const float*)d_in[6];
    const float* edge_b1 = (const float*)d_in[7];
    const float* edge_w2 = (const float*)d_in[8];
    const float* edge_b2 = (const float*)d_in[9];
    const float* node_w1 = (const float*)d_in[10];
    const float* node_b1 = (const float*)d_in[11];
    const float* node_w2 = (const float*)d_in[12];
    const float* node_b2 = (const float*)d_in[13];

    char* ws = (char*)d_ws;
    unsigned short* h0   = (unsigned short*)ws;                    // 12.8 MB
    unsigned short* h1   = (unsigned short*)(ws + 12800000);       // 12.8 MB
    unsigned short* swz  = (unsigned short*)(ws + 25600000);       // 589,824 B
    int* cnt             = (int*)(ws + 26189824);                  // 200,000 B
    int* ex              = (int*)(ws + 26389824);                  // 200,000 B
    int* bsums           = (int*)(ws + 26589824);                  // 1,024 B
    int* rsrt            = (int*)(ws + 26590848);                  // 3.2 MB
    unsigned short* S0   = (unsigned short*)(ws + 29790848);       // 12.8 MB
    unsigned short* D0   = (unsigned short*)(ws + 42590848);       // 12.8 MB
    unsigned short* S1   = (unsigned short*)(ws + 55390848);       // 12.8 MB
    unsigned short* D1   = (unsigned short*)(ws + 68190848);       // 12.8 MB
    float* Mtmp          = (float*)(ws + 80990848);                // 196,608 B
    float* Vtmp          = (float*)(ws + 81187456);                // 1,536 B
    int* ex2             = (int*)(ws + 81188992);                  // 200,000 B
    int* rank            = (int*)(ws + 81388992);                  // 3.2 MB -> end 84,588,992

    const int* rowp = ei;            // edge_index[0] = source
    const int* colp = ei + N_EDGES;  // edge_index[1] = destination

    hipMemsetAsync(cnt, 0, (size_t)N_NODES * 4, stream);

    k1_fused<<<EDGE_BLOCKS + MFOLD_BLOCKS + NODE_TILES + SWZA_BLOCKS, 256, 0, stream>>>(
        colp, cnt, rank, edge_w2, node_w1, edge_b2, Mtmp, Vtmp,
        x, enc_w, enc_b, h0, edge_w1, node_w2, swz);
    k2a_scan1_swizzle<<<SCAN_BLOCKS + SWZB_BLOCKS, 256, 0, stream>>>(
        cnt, ex, bsums, node_w1, Mtmp, swz);
    k3_scatter_sd<<<EDGE_BLOCKS + NODE_TILES, 256, 0, stream>>>(
        rowp, colp, ex, bsums, rank, rsrt, ex2,
        h0, swz /*L0 w1cat*/, edge_b1 /*fold L0 bias into D*/, S0, D0);

    unsigned short* Sc = S0; unsigned short* Dc = D0;
    unsigned short* Sn = S1; unsigned short* Dn = D1;
    unsigned short* hc = h0; unsigned short* hx = h1;
    for (int L = 0; L < 3; L++) {
        unsigned short* base = swz + (size_t)L * 98304;
        unsigned short* next = swz + (size_t)(L + 1) * 98304;   // w1cat of next layer
        if (L < 2) {
            layer_kernel<0><<<NODE_TILES, 512, 0, stream>>>(
                Sc, Dc, rsrt, ex2, hc, hx,
                base + 49152, node_b1 + (size_t)L * HID, Vtmp + (size_t)L * HID,
                base + 81920, node_b2 + (size_t)L * HID,
                next, edge_b1 + (size_t)(L + 1) * HID, Sn, Dn,
                dec_w, dec_b, (float*)d_out);
            { unsigned short* tp;
              tp = Sc; Sc = Sn; Sn = tp;
              tp = Dc; Dc = Dn; Dn = tp;
              tp = hc; hc = hx; hx = tp; }
        } else {
            layer_kernel<1><<<NODE_TILES, 512, 0, stream>>>(
                Sc, Dc, rsrt, ex2, hc, hx /*unused*/,
                base + 49152, node_b1 + (size_t)L * HID, Vtmp + (size_t)L * HID,
                base + 81920, node_b2 + (size_t)L * HID,
                base /*unused*/, edge_b1 /*unused*/, Sn /*unused*/, Dn /*unused*/,
                dec_w, dec_b, (float*)d_out);
        }
    }
}